// Round 3
// baseline (197.804 us; speedup 1.0000x reference)
//
#include <hip/hip_runtime.h>

// Fused causal attention head: B=8, T=2048, C=1024, H=128 (fp32 in/out).
//   q,k,v = x@W{q,k,v};  out = softmax(tril(q k^T * C^-0.5)) @ v
// Pipeline:
//   prep_wt : W (1024x128 fp32) -> Wt bf16 [384][1024] (transposed; Wq pre-scaled
//             by C^-0.5 * log2(e) so softmax runs in exp2 domain)
//   proj    : X@W via 16x16x32 bf16 MFMA, no LDS; 16 rows x 384 cols per block,
//             1024 blocks -> 4 blocks/CU. A direct from x + cvt, B from L2 Wt.
//   attn    : flash attention; 4 waves/block share 16 q-rows, split the kv range
//             4 ways, flash-combine partials in LDS. NO launch-bounds min-waves:
//             round-2's (256,4) capped VGPR at 64 -> spilled the S/o accumulators
//             (WRITE_SIZE showed +20 MB of scratch traffic). Let it have ~128.
// Workspace layout (~13 MB): [0,768K) Wt  [1M,5M) Qb  [5M,9M) Kb  [9M,13M) VT

#define B_ 8
#define T_ 2048
#define C_ 1024
#define H_ 128

typedef __attribute__((ext_vector_type(4))) float  f32x4;
typedef __attribute__((ext_vector_type(8))) __bf16 bf16x8;

#define QSCALE (0.03125f * 1.44269504088896340736f)  // C^-0.5 * log2(e)

static __device__ __forceinline__ short f2bf(float f) {
  union { __bf16 b; short s; } u;
  u.b = (__bf16)f;
  return u.s;
}

// ---------------- prep: Wt[n][k] = W_sel[k][n%128] * (n<128 ? QSCALE : 1) ---------
// grid 48 = 3 matrices x 16 k-chunks of 64. LDS transpose: coalesced both sides.
__global__ void prep_wt(const float* __restrict__ Wq, const float* __restrict__ Wk,
                        const float* __restrict__ Wv, short* __restrict__ Wt) {
  __shared__ float L[64 * 129];
  const int mtx = blockIdx.x >> 4, kc = blockIdx.x & 15;
  const int k0 = kc * 64;
  const float* W = (mtx == 0) ? Wq : (mtx == 1 ? Wk : Wv);
  const float s = (mtx == 0) ? QSCALE : 1.0f;
  for (int i = threadIdx.x; i < 64 * 128; i += 256) {
    int kk = i >> 7, c = i & 127;
    L[kk * 129 + c] = W[(size_t)(k0 + kk) * H_ + c] * s;
  }
  __syncthreads();
  for (int i = threadIdx.x; i < 128 * 64; i += 256) {
    int n = i >> 6, kk = i & 63;
    Wt[(size_t)(mtx * 128 + n) * C_ + k0 + kk] = f2bf(L[kk * 129 + n]);
  }
}

// ---------------- proj: 16 rows x 384 cols per block, no LDS ----------------------
// 4 waves; wave wv covers cols [wv*96, wv*96+96), rows m0..m0+15 (1 row-frag).
__global__ __launch_bounds__(256) void proj(const float* __restrict__ x,
                                            const short* __restrict__ Wt,
                                            short* __restrict__ Qb,
                                            short* __restrict__ Kb,
                                            short* __restrict__ VT) {
  const int tid = threadIdx.x, lane = tid & 63, wv = tid >> 6;
  const int cg = lane & 15, rg = lane >> 4;
  const int m0 = blockIdx.x * 16;
  const float* xb = x + (size_t)m0 * C_;

  f32x4 acc[6];
#pragma unroll
  for (int j = 0; j < 6; ++j) {
    f32x4 z = {0.f, 0.f, 0.f, 0.f};
    acc[j] = z;
  }

#pragma unroll 2
  for (int kk = 0; kk < C_; kk += 32) {
    const float* p = &xb[(size_t)cg * C_ + kk + rg * 8];
    f32x4 a0 = *(const f32x4*)p;
    f32x4 a1 = *(const f32x4*)(p + 4);
    bf16x8 af;
    af[0] = (__bf16)a0[0]; af[1] = (__bf16)a0[1];
    af[2] = (__bf16)a0[2]; af[3] = (__bf16)a0[3];
    af[4] = (__bf16)a1[0]; af[5] = (__bf16)a1[1];
    af[6] = (__bf16)a1[2]; af[7] = (__bf16)a1[3];
#pragma unroll
    for (int nf = 0; nf < 6; ++nf) {
      int n = wv * 96 + nf * 16 + cg;
      bf16x8 bfr = *(const bf16x8*)&Wt[(size_t)n * C_ + kk + rg * 8];
      acc[nf] = __builtin_amdgcn_mfma_f32_16x16x32_bf16(af, bfr, acc[nf], 0, 0, 0);
    }
  }

  // epilogue: D frag row=(lane>>4)*4+r, col=lane&15
#pragma unroll
  for (int nf = 0; nf < 6; ++nf) {
    int n = wv * 96 + nf * 16 + cg;
    int rowb = m0 + rg * 4;
    f32x4 v = acc[nf];
    if (n < 128) {
#pragma unroll
      for (int r = 0; r < 4; ++r)
        Qb[(size_t)(rowb + r) * H_ + n] = f2bf(v[r]);
    } else if (n < 256) {
#pragma unroll
      for (int r = 0; r < 4; ++r)
        Kb[(size_t)(rowb + r) * H_ + (n - 128)] = f2bf(v[r]);
    } else {
      int h = n - 256;
#pragma unroll
      for (int r = 0; r < 4; ++r) {
        int m = rowb + r;
        VT[((size_t)((m >> 11) * H_ + h)) * T_ + (m & (T_ - 1))] = f2bf(v[r]);
      }
    }
  }
}

// ---------------- attn: 16 q-rows per block, kv range split across 4 waves --------
// grid 1024: bid&7 = batch (XCD-local K/V), 127-(bid>>3) = q-group (largest first).
__global__ __launch_bounds__(256) void attn(const short* __restrict__ Qb,
                                            const short* __restrict__ Kb,
                                            const short* __restrict__ VT,
                                            float* __restrict__ out) {
  __shared__ __align__(16) float OC[4][16 * 128];   // 32 KB; P aliased on top
  __shared__ float Mml[4][16], Lml[4][16];
  const int tid = threadIdx.x, lane = tid & 63, wv = tid >> 6;
  const int cg = lane & 15, rg = lane >> 4;
  const int bid = blockIdx.x;
  const int b = bid & 7;
  const int qg = 127 - (bid >> 3);
  const int q0 = qg << 4;
  const int NT = (qg + 4) >> 2;          // ceil((q0+16)/64) kv-tiles of 64
  const int SPW = (NT + 3) >> 2;         // tiles per wave
  const int t0 = wv * SPW;
  const int t1 = (t0 + SPW < NT) ? (t0 + SPW) : NT;

  const short* Qp = Qb + (size_t)(b * T_ + q0) * H_;
  const short* Kp = Kb + (size_t)(b * T_) * H_;
  const short* Vp = VT + (size_t)(b * H_) * T_;
  short* Pw = (short*)&OC[wv][0];        // 2 KB per-wave P buffer (alias, swizzled)
  const float NEG_INF = -__builtin_inff();

  // Q frags: A[row=lane&15][k = ks*32 + (lane>>4)*8 + j]
  bf16x8 qf[4];
#pragma unroll
  for (int ks = 0; ks < 4; ++ks)
    qf[ks] = *(const bf16x8*)&Qp[(size_t)cg * H_ + ks * 32 + rg * 8];

  f32x4 o[8];
#pragma unroll
  for (int f = 0; f < 8; ++f) { f32x4 z = {0.f, 0.f, 0.f, 0.f}; o[f] = z; }
  float m[4], lsum[4];
#pragma unroll
  for (int r = 0; r < 4; ++r) { m[r] = NEG_INF; lsum[r] = 0.0f; }

  for (int t = t0; t < t1; ++t) {
    const int kv0 = t * 64;
    f32x4 S[4];
#pragma unroll
    for (int nf = 0; nf < 4; ++nf) { f32x4 z = {0.f, 0.f, 0.f, 0.f}; S[nf] = z; }

    // S = Q K^T (scale + log2e folded into Q)
#pragma unroll
    for (int nf = 0; nf < 4; ++nf) {
#pragma unroll
      for (int ks = 0; ks < 4; ++ks) {
        bf16x8 kfr = *(const bf16x8*)&Kp[(size_t)(kv0 + nf * 16 + cg) * H_ + ks * 32 + rg * 8];
        S[nf] = __builtin_amdgcn_mfma_f32_16x16x32_bf16(qf[ks], kfr, S[nf], 0, 0, 0);
      }
    }

    // causal mask: only the globally-last tile straddles the diagonal
    if (t == NT - 1) {
#pragma unroll
      for (int nf = 0; nf < 4; ++nf) {
#pragma unroll
        for (int r = 0; r < 4; ++r) {
          int kv = kv0 + nf * 16 + cg;
          int q = q0 + rg * 4 + r;
          if (kv > q) S[nf][r] = NEG_INF;
        }
      }
    }

    // online softmax (exp2 domain); row-max over the 16-lane group
    float sf[4];
#pragma unroll
    for (int r = 0; r < 4; ++r) {
      float pm = fmaxf(fmaxf(S[0][r], S[1][r]), fmaxf(S[2][r], S[3][r]));
      pm = fmaxf(pm, __shfl_xor(pm, 1));
      pm = fmaxf(pm, __shfl_xor(pm, 2));
      pm = fmaxf(pm, __shfl_xor(pm, 4));
      pm = fmaxf(pm, __shfl_xor(pm, 8));
      float mn = fmaxf(m[r], pm);
      sf[r] = exp2f(m[r] - mn);
      m[r] = mn;
      lsum[r] *= sf[r];
    }

    // P = exp2(S - m) -> bf16 in per-wave LDS (16B-slot swizzle: slot ^= row&7)
#pragma unroll
    for (int nf = 0; nf < 4; ++nf) {
#pragma unroll
      for (int r = 0; r < 4; ++r) {
        float p = exp2f(S[nf][r] - m[r]);
        lsum[r] += p;
        int row = rg * 4 + r, col = nf * 16 + cg;
        Pw[row * 64 + ((((col >> 3) ^ (row & 7))) << 3) + (col & 7)] = f2bf(p);
      }
    }

    // rescale O
#pragma unroll
    for (int f = 0; f < 8; ++f) {
#pragma unroll
      for (int r = 0; r < 4; ++r) o[f][r] *= sf[r];
    }

    // O += P V
#pragma unroll
    for (int ksl = 0; ksl < 2; ++ksl) {
      int slot = ksl * 4 + rg;
      bf16x8 pa = *(const bf16x8*)&Pw[cg * 64 + ((slot ^ (cg & 7)) << 3)];
#pragma unroll
      for (int hf = 0; hf < 8; ++hf) {
        bf16x8 vb = *(const bf16x8*)&Vp[(size_t)(hf * 16 + cg) * T_ + kv0 + ksl * 32 + rg * 8];
        o[hf] = __builtin_amdgcn_mfma_f32_16x16x32_bf16(pa, vb, o[hf], 0, 0, 0);
      }
    }
  }

  // per-wave row-sum of l across the 16-lane group
#pragma unroll
  for (int r = 0; r < 4; ++r) {
    float l = lsum[r];
    l += __shfl_xor(l, 1);
    l += __shfl_xor(l, 2);
    l += __shfl_xor(l, 4);
    l += __shfl_xor(l, 8);
    lsum[r] = l;
  }
  if (cg == 0) {
#pragma unroll
    for (int r = 0; r < 4; ++r) {
      Mml[wv][rg * 4 + r] = m[r];
      Lml[wv][rg * 4 + r] = lsum[r];
    }
  }
  // park partial O in LDS (overwrites this wave's P region — loop is done)
#pragma unroll
  for (int hf = 0; hf < 8; ++hf)
#pragma unroll
    for (int r = 0; r < 4; ++r)
      OC[wv][(rg * 4 + r) * 128 + hf * 16 + cg] = o[hf][r];
  __syncthreads();

  // flash-combine the 4 partials, normalize, store fp32 coalesced
  for (int i = tid; i < 16 * 128; i += 256) {
    int row = i >> 7, col = i & 127;
    float m0v = Mml[0][row], m1v = Mml[1][row], m2v = Mml[2][row], m3v = Mml[3][row];
    float ms = fmaxf(fmaxf(m0v, m1v), fmaxf(m2v, m3v));
    float accv = 0.f, lacc = 0.f;
#pragma unroll
    for (int w = 0; w < 4; ++w) {
      float sc = exp2f(Mml[w][row] - ms);
      lacc += sc * Lml[w][row];
      accv += sc * OC[w][row * 128 + col];
    }
    out[(size_t)(b * T_ + q0 + row) * H_ + col] = accv / lacc;
  }
}

extern "C" void kernel_launch(void* const* d_in, const int* in_sizes, int n_in,
                              void* d_out, int out_size, void* d_ws, size_t ws_size,
                              hipStream_t stream) {
  const float* x  = (const float*)d_in[0];
  const float* Wq = (const float*)d_in[1];
  const float* Wk = (const float*)d_in[2];
  const float* Wv = (const float*)d_in[3];
  float* out = (float*)d_out;
  char* ws = (char*)d_ws;

  short* Wt = (short*)(ws);                          // 768 KB
  short* Qb = (short*)(ws + ((size_t)1 << 20));      // 4 MB
  short* Kb = (short*)(ws + ((size_t)5 << 20));      // 4 MB
  short* VT = (short*)(ws + ((size_t)9 << 20));      // 4 MB  (total 13 MB)

  prep_wt<<<dim3(48), dim3(256), 0, stream>>>(Wq, Wk, Wv, Wt);
  proj<<<dim3(1024), dim3(256), 0, stream>>>(x, Wt, Qb, Kb, VT);
  attn<<<dim3(1024), dim3(256), 0, stream>>>(Qb, Kb, VT, out);
}

// Round 4
// 152.556 us; speedup vs baseline: 1.2966x; 1.2966x over previous
//
#include <hip/hip_runtime.h>

// Fused causal attention head: B=8, T=2048, C=1024, H=128 (fp32 in/out).
//   q,k,v = x@W{q,k,v};  out = softmax(tril(q k^T * C^-0.5)) @ v
// Pipeline:
//   prep_wt : W -> Wt bf16 [384][1024] transposed; Wq pre-scaled by C^-0.5*log2e.
//   proj    : m97-style 2-phase GEMM. BM=64, BK=128, 4 waves, wave = 64r x 96c
//             (M_rep=4 -> 24 MFMA per k-step vs round-3's 6: fixes the
//             latency-bound 3.9% MfmaUtil). A fp32 in dbuf LDS via
//             global_load_lds w16, XOR-swizzled; B direct from L2-resident Wt.
//   attn    : flash attn, swapped QK^T (S^T = mfma(K,Q)) -> P is lane-local:
//             row-max = 2 shfl_xor (was 16), softmax state scalar, and PV uses
//             16x16x16 MFMA whose B-frag layout == S^T acc layout -> P feeds PV
//             straight from registers (no LDS, no permutes).
// Workspace (~13 MB): [0,768K) Wt  [1M,5M) Qb  [5M,9M) Kb  [9M,13M) VT

#define B_ 8
#define T_ 2048
#define C_ 1024
#define H_ 128

typedef __attribute__((ext_vector_type(4))) float  f32x4;
typedef __attribute__((ext_vector_type(8))) __bf16 bf16x8;
typedef __attribute__((ext_vector_type(4))) __bf16 bf16x4;
typedef __attribute__((ext_vector_type(4))) short  short4v;

#define QSCALE (0.03125f * 1.44269504088896340736f)  // C^-0.5 * log2(e)

static __device__ __forceinline__ short f2bf(float f) {
  union { __bf16 b; short s; } u;
  u.b = (__bf16)f;
  return u.s;
}

static __device__ __forceinline__ unsigned packbf2(float lo, float hi) {
  union { __bf16 b; unsigned short s; } a, c;
  a.b = (__bf16)lo; c.b = (__bf16)hi;
  return (unsigned)a.s | ((unsigned)c.s << 16);
}

// D = A(16x16) * B(16x16) + C, bf16 inputs, K=16.
// A-frag: A[row=lane&15][k=(lane>>4)*4+j]; B-frag: B[k=(lane>>4)*4+j][col=lane&15].
static __device__ __forceinline__ f32x4 mfma16(unsigned a0, unsigned a1,
                                               unsigned b0, unsigned b1, f32x4 c) {
#if __has_builtin(__builtin_amdgcn_mfma_f32_16x16x16_bf16)
  union { unsigned u[2]; bf16x4 v; } ua, ub;
  ua.u[0] = a0; ua.u[1] = a1; ub.u[0] = b0; ub.u[1] = b1;
  return __builtin_amdgcn_mfma_f32_16x16x16_bf16(ua.v, ub.v, c, 0, 0, 0);
#elif __has_builtin(__builtin_amdgcn_mfma_f32_16x16x16bf16_1k)
  union { unsigned u[2]; short4v v; } ua, ub;
  ua.u[0] = a0; ua.u[1] = a1; ub.u[0] = b0; ub.u[1] = b1;
  return __builtin_amdgcn_mfma_f32_16x16x16bf16_1k(ua.v, ub.v, c, 0, 0, 0);
#else
  union { unsigned u[2]; short4v v; } ua, ub;
  ua.u[0] = a0; ua.u[1] = a1; ub.u[0] = b0; ub.u[1] = b1;
  f32x4 d = c;
  asm volatile("v_mfma_f32_16x16x16_bf16 %0, %1, %2, %0"
               : "+v"(d) : "v"(ua.v), "v"(ub.v));
  return d;
#endif
}

static __device__ __forceinline__ void gload_lds16(const void* g, void* l) {
  __builtin_amdgcn_global_load_lds(
      (const __attribute__((address_space(1))) unsigned int*)g,
      (__attribute__((address_space(3))) unsigned int*)l, 16, 0, 0);
}

// ---------------- prep: Wt[n][k] = W_sel[k][n%128] * (n<128 ? QSCALE : 1) ---------
__global__ void prep_wt(const float* __restrict__ Wq, const float* __restrict__ Wk,
                        const float* __restrict__ Wv, short* __restrict__ Wt) {
  __shared__ float L[64 * 129];
  const int mtx = blockIdx.x >> 4, kc = blockIdx.x & 15;
  const int k0 = kc * 64;
  const float* W = (mtx == 0) ? Wq : (mtx == 1 ? Wk : Wv);
  const float s = (mtx == 0) ? QSCALE : 1.0f;
  for (int i = threadIdx.x; i < 64 * 128; i += 256) {
    int kk = i >> 7, c = i & 127;
    L[kk * 129 + c] = W[(size_t)(k0 + kk) * H_ + c] * s;
  }
  __syncthreads();
  for (int i = threadIdx.x; i < 128 * 64; i += 256) {
    int n = i >> 6, kk = i & 63;
    Wt[(size_t)(mtx * 128 + n) * C_ + k0 + kk] = f2bf(L[kk * 129 + n]);
  }
}

// ---------------- proj: BM=64 x 384 cols, BK=128, dbuf LDS, 4 waves --------------
// wave wv: all 64 rows x cols [wv*96, wv*96+96). 24 MFMA per k-step of 32.
__global__ __launch_bounds__(256) void proj(const float* __restrict__ x,
                                            const short* __restrict__ Wt,
                                            short* __restrict__ Qb,
                                            short* __restrict__ Kb,
                                            short* __restrict__ VT) {
  __shared__ __align__(16) float At[2][64 * 128];  // 2 x 32 KB
  const int tid = threadIdx.x, lane = tid & 63, wv = tid >> 6;
  const int cg = lane & 15, rg = lane >> 4;
  const int m0 = blockIdx.x * 64;
  const float* xblk = x + (size_t)m0 * C_;

  f32x4 acc[4][6];
#pragma unroll
  for (int i = 0; i < 4; ++i)
#pragma unroll
    for (int j = 0; j < 6; ++j) {
      f32x4 z = {0.f, 0.f, 0.f, 0.f};
      acc[i][j] = z;
    }

  // stage BK-tile kt into buffer bf: 2048 slots of 16B, dest linear,
  // source pre-swizzled (slot ^= row&7) so swizzled ds_read is conflict-free.
#define STAGE(bf, kt)                                                          \
  {                                                                            \
    int k0s = (kt) * 128;                                                      \
    _Pragma("unroll") for (int it = 0; it < 8; ++it) {                         \
      int slotbase = it * 256 + wv * 64; /* wave-uniform */                    \
      int slot = slotbase + lane;                                              \
      int r = slot >> 5, s5 = slot & 31;                                       \
      gload_lds16(xblk + (size_t)r * C_ + k0s + ((s5 ^ (r & 7)) << 2),         \
                  &At[bf][slotbase * 4]);                                      \
    }                                                                          \
  }

  STAGE(0, 0);
  __syncthreads();

  for (int kt = 0; kt < 8; ++kt) {
    const int cur = kt & 1;
    if (kt < 7) STAGE(cur ^ 1, kt + 1);

#pragma unroll
    for (int ks = 0; ks < 4; ++ks) {
      bf16x8 af[4];
#pragma unroll
      for (int fm = 0; fm < 4; ++fm) {
        int r = fm * 16 + cg;
        int s0 = ks * 8 + rg * 2;
        f32x4 a0 = *(const f32x4*)&At[cur][r * 128 + (((s0    ) ^ (r & 7)) << 2)];
        f32x4 a1 = *(const f32x4*)&At[cur][r * 128 + (((s0 + 1) ^ (r & 7)) << 2)];
        bf16x8 tv;
        tv[0] = (__bf16)a0[0]; tv[1] = (__bf16)a0[1];
        tv[2] = (__bf16)a0[2]; tv[3] = (__bf16)a0[3];
        tv[4] = (__bf16)a1[0]; tv[5] = (__bf16)a1[1];
        tv[6] = (__bf16)a1[2]; tv[7] = (__bf16)a1[3];
        af[fm] = tv;
      }
#pragma unroll
      for (int nf = 0; nf < 6; ++nf) {
        int n = wv * 96 + nf * 16 + cg;
        bf16x8 bfr = *(const bf16x8*)&Wt[(size_t)n * C_ + kt * 128 + ks * 32 + rg * 8];
#pragma unroll
        for (int fm = 0; fm < 4; ++fm)
          acc[fm][nf] = __builtin_amdgcn_mfma_f32_16x16x32_bf16(af[fm], bfr, acc[fm][nf], 0, 0, 0);
      }
    }
    __syncthreads();  // staged(kt+1) complete; all reads of cur done before overwrite
  }
#undef STAGE

  // epilogue: D frag row=(lane>>4)*4+r, col=lane&15
#pragma unroll
  for (int fm = 0; fm < 4; ++fm) {
#pragma unroll
    for (int nf = 0; nf < 6; ++nf) {
      int n = wv * 96 + nf * 16 + cg;
      int rowb = m0 + fm * 16 + rg * 4;
      f32x4 v = acc[fm][nf];
      if (n < 128) {
#pragma unroll
        for (int r = 0; r < 4; ++r)
          Qb[(size_t)(rowb + r) * H_ + n] = f2bf(v[r]);
      } else if (n < 256) {
#pragma unroll
        for (int r = 0; r < 4; ++r)
          Kb[(size_t)(rowb + r) * H_ + (n - 128)] = f2bf(v[r]);
      } else {
        int h = n - 256;
#pragma unroll
        for (int r = 0; r < 4; ++r) {
          int m = rowb + r;
          VT[((size_t)((m >> 11) * H_ + h)) * T_ + (m & (T_ - 1))] = f2bf(v[r]);
        }
      }
    }
  }
}

// ---------------- attn: swapped QK^T, in-register softmax, K=16 PV ----------------
// grid 1024: bid&7 = batch (XCD-local K/V), 127-(bid>>3) = q-group (largest first).
// 4 waves share 16 q-rows, split kv range; flash-combine partials in LDS.
#define OCW 132  // 128 + 4 pad (breaks 512B-stride bank conflicts)
__global__ __launch_bounds__(256) void attn(const short* __restrict__ Qb,
                                            const short* __restrict__ Kb,
                                            const short* __restrict__ VT,
                                            float* __restrict__ out) {
  __shared__ __align__(16) float OC[4][16 * OCW];
  __shared__ float Mml[4][16], Lml[4][16];
  const int tid = threadIdx.x, lane = tid & 63, wv = tid >> 6;
  const int cg = lane & 15, rg = lane >> 4;
  const int bid = blockIdx.x;
  const int b = bid & 7;
  const int qg = 127 - (bid >> 3);
  const int q0 = qg << 4;
  const int NT = (qg + 4) >> 2;          // ceil((q0+16)/64) kv-tiles of 64
  const int SPW = (NT + 3) >> 2;
  const int t0 = wv * SPW;
  const int t1 = (t0 + SPW < NT) ? (t0 + SPW) : NT;

  const short* Qp = Qb + (size_t)(b * T_ + q0) * H_;
  const short* Kp = Kb + (size_t)(b * T_) * H_;
  const short* Vp = VT + (size_t)(b * H_) * T_;
  const float NEG_INF = -__builtin_inff();
  const int q = q0 + cg;                 // this lane's q row (S^T col)

  // Q frags (B-operand for swapped QK^T): lane (cg,rg) holds Q[q=cg][k=ks*32+rg*8+j]
  bf16x8 qf[4];
#pragma unroll
  for (int ks = 0; ks < 4; ++ks)
    qf[ks] = *(const bf16x8*)&Qp[(size_t)cg * H_ + ks * 32 + rg * 8];

  f32x4 o[8];                            // O^T: o[hf][r] = O[q=cg][h=hf*16+rg*4+r]
#pragma unroll
  for (int f = 0; f < 8; ++f) { f32x4 z = {0.f, 0.f, 0.f, 0.f}; o[f] = z; }
  float m = NEG_INF, lsum = 0.0f;

  for (int t = t0; t < t1; ++t) {
    const int kv0 = t * 64;
    f32x4 s[4];
#pragma unroll
    for (int nf = 0; nf < 4; ++nf) { f32x4 z = {0.f, 0.f, 0.f, 0.f}; s[nf] = z; }

    // S^T = K Q^T: s[nf][r] = S[q=cg][kv = kv0+nf*16+rg*4+r]
    __builtin_amdgcn_s_setprio(1);
#pragma unroll
    for (int nf = 0; nf < 4; ++nf) {
#pragma unroll
      for (int ks = 0; ks < 4; ++ks) {
        bf16x8 kfr = *(const bf16x8*)&Kp[(size_t)(kv0 + nf * 16 + cg) * H_ + ks * 32 + rg * 8];
        s[nf] = __builtin_amdgcn_mfma_f32_16x16x32_bf16(kfr, qf[ks], s[nf], 0, 0, 0);
      }
    }
    __builtin_amdgcn_s_setprio(0);

    // causal mask (only the globally-last tile straddles the diagonal)
    if (t == NT - 1) {
#pragma unroll
      for (int nf = 0; nf < 4; ++nf)
#pragma unroll
        for (int r = 0; r < 4; ++r)
          if (kv0 + nf * 16 + rg * 4 + r > q) s[nf][r] = NEG_INF;
    }

    // online softmax, exp2 domain. Row-max: own 16 regs + 2 shfl_xor across rg.
    float pm = s[0][0];
#pragma unroll
    for (int nf = 0; nf < 4; ++nf)
#pragma unroll
      for (int r = 0; r < 4; ++r) pm = fmaxf(pm, s[nf][r]);
    pm = fmaxf(pm, __shfl_xor(pm, 16));
    pm = fmaxf(pm, __shfl_xor(pm, 32));
    float mn = fmaxf(m, pm);
    float sf = exp2f(m - mn);            // first tile: exp2(-inf) = 0
    m = mn;
    lsum *= sf;

    // P = exp2(S - m), packed bf16 pairs; stays in registers (PV B-frag layout)
    unsigned pk[4][2];
#pragma unroll
    for (int nf = 0; nf < 4; ++nf) {
      float p0 = exp2f(s[nf][0] - m), p1 = exp2f(s[nf][1] - m);
      float p2 = exp2f(s[nf][2] - m), p3 = exp2f(s[nf][3] - m);
      lsum += (p0 + p1) + (p2 + p3);
      pk[nf][0] = packbf2(p0, p1);
      pk[nf][1] = packbf2(p2, p3);
    }

#pragma unroll
    for (int f = 0; f < 8; ++f) {
#pragma unroll
      for (int r = 0; r < 4; ++r) o[f][r] *= sf;
    }

    // O^T += V^T P^T via 16x16x16: A = V^T[h][kv], B = P^T[kv][q] (own regs!)
    __builtin_amdgcn_s_setprio(1);
#pragma unroll
    for (int nf = 0; nf < 4; ++nf) {
      const unsigned b0 = pk[nf][0], b1 = pk[nf][1];
      const short* vrow = &Vp[kv0 + nf * 16 + rg * 4];
#pragma unroll
      for (int hf = 0; hf < 8; ++hf) {
        const unsigned* vp = (const unsigned*)&vrow[(size_t)(hf * 16 + cg) * T_];
        o[hf] = mfma16(vp[0], vp[1], b0, b1, o[hf]);
      }
    }
    __builtin_amdgcn_s_setprio(0);
  }

  // reduce l across rg groups (same q)
  lsum += __shfl_xor(lsum, 16);
  lsum += __shfl_xor(lsum, 32);
  if (lane < 16) {                       // rg==0, cg = lane
    Mml[wv][lane] = m;
    Lml[wv][lane] = lsum;
  }
  // park partial O^T in LDS as [q][h] (f32x4 stores, padded stride)
#pragma unroll
  for (int hf = 0; hf < 8; ++hf)
    *(f32x4*)&OC[wv][cg * OCW + hf * 16 + rg * 4] = o[hf];
  __syncthreads();

  // flash-combine the 4 partials, normalize, store fp32 coalesced
  for (int i = tid; i < 16 * 128; i += 256) {
    int row = i >> 7, col = i & 127;
    float m0v = Mml[0][row], m1v = Mml[1][row], m2v = Mml[2][row], m3v = Mml[3][row];
    float ms = fmaxf(fmaxf(m0v, m1v), fmaxf(m2v, m3v));
    float accv = 0.f, lacc = 0.f;
#pragma unroll
    for (int w = 0; w < 4; ++w) {
      float sc = exp2f(Mml[w][row] - ms);
      lacc += sc * Lml[w][row];
      accv += sc * OC[w][row * OCW + col];
    }
    out[(size_t)(b * T_ + q0 + row) * H_ + col] = accv / lacc;
  }
}

extern "C" void kernel_launch(void* const* d_in, const int* in_sizes, int n_in,
                              void* d_out, int out_size, void* d_ws, size_t ws_size,
                              hipStream_t stream) {
  const float* x  = (const float*)d_in[0];
  const float* Wq = (const float*)d_in[1];
  const float* Wk = (const float*)d_in[2];
  const float* Wv = (const float*)d_in[3];
  float* out = (float*)d_out;
  char* ws = (char*)d_ws;

  short* Wt = (short*)(ws);                          // 768 KB
  short* Qb = (short*)(ws + ((size_t)1 << 20));      // 4 MB
  short* Kb = (short*)(ws + ((size_t)5 << 20));      // 4 MB
  short* VT = (short*)(ws + ((size_t)9 << 20));      // 4 MB  (total 13 MB)

  prep_wt<<<dim3(48), dim3(256), 0, stream>>>(Wq, Wk, Wv, Wt);
  proj<<<dim3(256), dim3(256), 0, stream>>>(x, Wt, Qb, Kb, VT);
  attn<<<dim3(1024), dim3(256), 0, stream>>>(Qb, Kb, VT, out);
}

// Round 5
// 129.098 us; speedup vs baseline: 1.5322x; 1.1817x over previous
//
#include <hip/hip_runtime.h>

// Fused causal attention head: B=8, T=2048, C=1024, H=128 (fp32 in/out).
//   q,k,v = x@W{q,k,v};  out = softmax(tril(q k^T * C^-0.5)) @ v
// Pipeline:
//   prep_wt : W -> Wt bf16 [384][1024] transposed; Wq pre-scaled by C^-0.5*log2e.
//   proj    : 2-phase GEMM, BM=32, BK=128, grid 512 (2 blocks/CU so barrier
//             drains overlap across blocks), dbuf LDS via global_load_lds w16.
//   attn    : flash attn, swapped QK^T (S^T = mfma(K,Q)), QBLK=32 (2 q-col
//             groups) -> each K/V load feeds 2x MFMAs vs round 4. P stays in
//             registers (S^T acc layout == 16x16x16 B-frag layout). 4 waves
//             split the kv range, flash-combine partials in LDS.
// Workspace (~13 MB): [0,768K) Wt  [1M,5M) Qb  [5M,9M) Kb  [9M,13M) VT

#define B_ 8
#define T_ 2048
#define C_ 1024
#define H_ 128

typedef __attribute__((ext_vector_type(4))) float  f32x4;
typedef __attribute__((ext_vector_type(8))) __bf16 bf16x8;
typedef __attribute__((ext_vector_type(4))) __bf16 bf16x4;
typedef __attribute__((ext_vector_type(4))) short  short4v;

#define QSCALE (0.03125f * 1.44269504088896340736f)  // C^-0.5 * log2(e)

static __device__ __forceinline__ short f2bf(float f) {
  union { __bf16 b; short s; } u;
  u.b = (__bf16)f;
  return u.s;
}

static __device__ __forceinline__ unsigned packbf2(float lo, float hi) {
  union { __bf16 b; unsigned short s; } a, c;
  a.b = (__bf16)lo; c.b = (__bf16)hi;
  return (unsigned)a.s | ((unsigned)c.s << 16);
}

// D = A(16x16) * B(16x16) + C, bf16, K=16.
// A-frag: A[row=lane&15][k=(lane>>4)*4+j]; B-frag: B[k=(lane>>4)*4+j][col=lane&15].
static __device__ __forceinline__ f32x4 mfma16(unsigned a0, unsigned a1,
                                               unsigned b0, unsigned b1, f32x4 c) {
#if __has_builtin(__builtin_amdgcn_mfma_f32_16x16x16_bf16)
  union { unsigned u[2]; bf16x4 v; } ua, ub;
  ua.u[0] = a0; ua.u[1] = a1; ub.u[0] = b0; ub.u[1] = b1;
  return __builtin_amdgcn_mfma_f32_16x16x16_bf16(ua.v, ub.v, c, 0, 0, 0);
#elif __has_builtin(__builtin_amdgcn_mfma_f32_16x16x16bf16_1k)
  union { unsigned u[2]; short4v v; } ua, ub;
  ua.u[0] = a0; ua.u[1] = a1; ub.u[0] = b0; ub.u[1] = b1;
  return __builtin_amdgcn_mfma_f32_16x16x16bf16_1k(ua.v, ub.v, c, 0, 0, 0);
#else
  union { unsigned u[2]; short4v v; } ua, ub;
  ua.u[0] = a0; ua.u[1] = a1; ub.u[0] = b0; ub.u[1] = b1;
  f32x4 d = c;
  asm volatile("v_mfma_f32_16x16x16_bf16 %0, %1, %2, %0"
               : "+v"(d) : "v"(ua.v), "v"(ub.v));
  return d;
#endif
}

static __device__ __forceinline__ void gload_lds16(const void* g, void* l) {
  __builtin_amdgcn_global_load_lds(
      (const __attribute__((address_space(1))) unsigned int*)g,
      (__attribute__((address_space(3))) unsigned int*)l, 16, 0, 0);
}

// ---------------- prep: Wt[n][k] = W_sel[k][n%128] * (n<128 ? QSCALE : 1) ---------
__global__ void prep_wt(const float* __restrict__ Wq, const float* __restrict__ Wk,
                        const float* __restrict__ Wv, short* __restrict__ Wt) {
  __shared__ float L[64 * 129];
  const int mtx = blockIdx.x >> 4, kc = blockIdx.x & 15;
  const int k0 = kc * 64;
  const float* W = (mtx == 0) ? Wq : (mtx == 1 ? Wk : Wv);
  const float s = (mtx == 0) ? QSCALE : 1.0f;
  for (int i = threadIdx.x; i < 64 * 128; i += 256) {
    int kk = i >> 7, c = i & 127;
    L[kk * 129 + c] = W[(size_t)(k0 + kk) * H_ + c] * s;
  }
  __syncthreads();
  for (int i = threadIdx.x; i < 128 * 64; i += 256) {
    int n = i >> 6, kk = i & 63;
    Wt[(size_t)(mtx * 128 + n) * C_ + k0 + kk] = f2bf(L[kk * 129 + n]);
  }
}

// ---------------- proj: BM=32 x 384 cols, BK=128, dbuf LDS, 4 waves, grid 512 ----
// wave wv: 32 rows x cols [wv*96, wv*96+96). 12 MFMA per k-step of 32.
__global__ __launch_bounds__(256) void proj(const float* __restrict__ x,
                                            const short* __restrict__ Wt,
                                            short* __restrict__ Qb,
                                            short* __restrict__ Kb,
                                            short* __restrict__ VT) {
  __shared__ __align__(16) float At[2][32 * 128];  // 2 x 16 KB
  const int tid = threadIdx.x, lane = tid & 63, wv = tid >> 6;
  const int cg = lane & 15, rg = lane >> 4;
  const int m0 = blockIdx.x * 32;
  const float* xblk = x + (size_t)m0 * C_;

  f32x4 acc[2][6];
#pragma unroll
  for (int i = 0; i < 2; ++i)
#pragma unroll
    for (int j = 0; j < 6; ++j) {
      f32x4 z = {0.f, 0.f, 0.f, 0.f};
      acc[i][j] = z;
    }

  // stage BK-tile kt into buffer bf: 1024 slots of 16B, dest linear,
  // source pre-swizzled (slot ^= row&7) so swizzled ds_read is conflict-free.
#define STAGE(bf, kt)                                                          \
  {                                                                            \
    int k0s = (kt) * 128;                                                      \
    _Pragma("unroll") for (int it = 0; it < 4; ++it) {                         \
      int slotbase = it * 256 + wv * 64; /* wave-uniform */                    \
      int slot = slotbase + lane;                                              \
      int r = slot >> 5, s5 = slot & 31;                                       \
      gload_lds16(xblk + (size_t)r * C_ + k0s + ((s5 ^ (r & 7)) << 2),         \
                  &At[bf][slotbase * 4]);                                      \
    }                                                                          \
  }

  STAGE(0, 0);
  __syncthreads();

  for (int kt = 0; kt < 8; ++kt) {
    const int cur = kt & 1;
    if (kt < 7) STAGE(cur ^ 1, kt + 1);

#pragma unroll
    for (int ks = 0; ks < 4; ++ks) {
      bf16x8 af[2];
#pragma unroll
      for (int fm = 0; fm < 2; ++fm) {
        int r = fm * 16 + cg;
        int s0 = ks * 8 + rg * 2;
        f32x4 a0 = *(const f32x4*)&At[cur][r * 128 + (((s0    ) ^ (r & 7)) << 2)];
        f32x4 a1 = *(const f32x4*)&At[cur][r * 128 + (((s0 + 1) ^ (r & 7)) << 2)];
        bf16x8 tv;
        tv[0] = (__bf16)a0[0]; tv[1] = (__bf16)a0[1];
        tv[2] = (__bf16)a0[2]; tv[3] = (__bf16)a0[3];
        tv[4] = (__bf16)a1[0]; tv[5] = (__bf16)a1[1];
        tv[6] = (__bf16)a1[2]; tv[7] = (__bf16)a1[3];
        af[fm] = tv;
      }
#pragma unroll
      for (int nf = 0; nf < 6; ++nf) {
        int n = wv * 96 + nf * 16 + cg;
        bf16x8 bfr = *(const bf16x8*)&Wt[(size_t)n * C_ + kt * 128 + ks * 32 + rg * 8];
#pragma unroll
        for (int fm = 0; fm < 2; ++fm)
          acc[fm][nf] = __builtin_amdgcn_mfma_f32_16x16x32_bf16(af[fm], bfr, acc[fm][nf], 0, 0, 0);
      }
    }
    __syncthreads();  // staged(kt+1) complete; all reads of cur done before overwrite
  }
#undef STAGE

  // epilogue: D frag row=(lane>>4)*4+r, col=lane&15
#pragma unroll
  for (int fm = 0; fm < 2; ++fm) {
#pragma unroll
    for (int nf = 0; nf < 6; ++nf) {
      int n = wv * 96 + nf * 16 + cg;
      int rowb = m0 + fm * 16 + rg * 4;
      f32x4 v = acc[fm][nf];
      if (n < 128) {
#pragma unroll
        for (int r = 0; r < 4; ++r)
          Qb[(size_t)(rowb + r) * H_ + n] = f2bf(v[r]);
      } else if (n < 256) {
#pragma unroll
        for (int r = 0; r < 4; ++r)
          Kb[(size_t)(rowb + r) * H_ + (n - 128)] = f2bf(v[r]);
      } else {
        int h = n - 256;
#pragma unroll
        for (int r = 0; r < 4; ++r) {
          int m = rowb + r;
          VT[((size_t)((m >> 11) * H_ + h)) * T_ + (m & (T_ - 1))] = f2bf(v[r]);
        }
      }
    }
  }
}

// ---------------- attn: QBLK=32, swapped QK^T, in-register softmax/P --------------
// grid 512: bid&7 = batch (XCD-local K/V), 63-(bid>>3) = q-group (largest first).
// 4 waves share 32 q-rows, split kv range; flash-combine partials in LDS.
#define OCW 132  // 128 + 4 pad
__global__ __launch_bounds__(256) void attn(const short* __restrict__ Qb,
                                            const short* __restrict__ Kb,
                                            const short* __restrict__ VT,
                                            float* __restrict__ out) {
  __shared__ __align__(16) float OC[4][32 * OCW];   // 67.6 KB
  __shared__ float Mml[4][32], Lml[4][32];
  const int tid = threadIdx.x, lane = tid & 63, wv = tid >> 6;
  const int cg = lane & 15, rg = lane >> 4;
  const int bid = blockIdx.x;
  const int b = bid & 7;
  const int qg = 63 - (bid >> 3);
  const int q0 = qg << 5;
  const int NT = (q0 + 95) >> 6;         // ceil((q0+32)/64) kv-tiles of 64
  const int SPW = (NT + 3) >> 2;
  const int t0 = wv * SPW;
  const int t1 = (t0 + SPW < NT) ? (t0 + SPW) : NT;

  const short* Qp = Qb + (size_t)(b * T_ + q0) * H_;
  const short* Kp = Kb + (size_t)(b * T_) * H_;
  const short* Vp = VT + (size_t)(b * H_) * T_;
  const float NEG_INF = -__builtin_inff();

  // Q frags (B-operand for swapped QK^T): qf[qc][ks] = Q[q0+qc*16+cg][ks*32+rg*8..]
  bf16x8 qf[2][4];
#pragma unroll
  for (int qc = 0; qc < 2; ++qc)
#pragma unroll
    for (int ks = 0; ks < 4; ++ks)
      qf[qc][ks] = *(const bf16x8*)&Qp[(size_t)(qc * 16 + cg) * H_ + ks * 32 + rg * 8];

  f32x4 o[8][2];                         // O^T: o[hf][qc][r] = O[q][h=hf*16+rg*4+r]
#pragma unroll
  for (int f = 0; f < 8; ++f)
#pragma unroll
    for (int qc = 0; qc < 2; ++qc) { f32x4 z = {0.f, 0.f, 0.f, 0.f}; o[f][qc] = z; }
  float m[2] = {NEG_INF, NEG_INF}, lsum[2] = {0.0f, 0.0f};

  for (int t = t0; t < t1; ++t) {
    const int kv0 = t * 64;

    // batch all 16 K loads for this tile (issue before the MFMA cluster)
    bf16x8 kf[4][4];
#pragma unroll
    for (int nf = 0; nf < 4; ++nf)
#pragma unroll
      for (int ks = 0; ks < 4; ++ks)
        kf[nf][ks] = *(const bf16x8*)&Kp[(size_t)(kv0 + nf * 16 + cg) * H_ + ks * 32 + rg * 8];

    f32x4 s[4][2];
#pragma unroll
    for (int nf = 0; nf < 4; ++nf)
#pragma unroll
      for (int qc = 0; qc < 2; ++qc) { f32x4 z = {0.f, 0.f, 0.f, 0.f}; s[nf][qc] = z; }

    // S^T = K Q^T: s[nf][qc][r] = S[q=q0+qc*16+cg][kv = kv0+nf*16+rg*4+r]
    __builtin_amdgcn_s_setprio(1);
#pragma unroll
    for (int nf = 0; nf < 4; ++nf)
#pragma unroll
      for (int ks = 0; ks < 4; ++ks) {
        s[nf][0] = __builtin_amdgcn_mfma_f32_16x16x32_bf16(kf[nf][ks], qf[0][ks], s[nf][0], 0, 0, 0);
        s[nf][1] = __builtin_amdgcn_mfma_f32_16x16x32_bf16(kf[nf][ks], qf[1][ks], s[nf][1], 0, 0, 0);
      }
    __builtin_amdgcn_s_setprio(0);

    // causal mask (only the globally-last tile straddles the diagonal)
    if (t == NT - 1) {
#pragma unroll
      for (int nf = 0; nf < 4; ++nf)
#pragma unroll
        for (int qc = 0; qc < 2; ++qc)
#pragma unroll
          for (int r = 0; r < 4; ++r)
            if (kv0 + nf * 16 + rg * 4 + r > q0 + qc * 16 + cg) s[nf][qc][r] = NEG_INF;
    }

    // online softmax (exp2 domain), per q-col group
    unsigned pk[4][2][2];
#pragma unroll
    for (int qc = 0; qc < 2; ++qc) {
      float pm = s[0][qc][0];
#pragma unroll
      for (int nf = 0; nf < 4; ++nf)
#pragma unroll
        for (int r = 0; r < 4; ++r) pm = fmaxf(pm, s[nf][qc][r]);
      pm = fmaxf(pm, __shfl_xor(pm, 16));
      pm = fmaxf(pm, __shfl_xor(pm, 32));   // full row max (finite: kv0 <= q always)
      float mn = fmaxf(m[qc], pm);
      float sf = exp2f(m[qc] - mn);         // first tile: exp2(-inf) = 0
      m[qc] = mn;
      lsum[qc] *= sf;
#pragma unroll
      for (int nf = 0; nf < 4; ++nf) {
        float p0 = exp2f(s[nf][qc][0] - mn), p1 = exp2f(s[nf][qc][1] - mn);
        float p2 = exp2f(s[nf][qc][2] - mn), p3 = exp2f(s[nf][qc][3] - mn);
        lsum[qc] += (p0 + p1) + (p2 + p3);
        pk[nf][qc][0] = packbf2(p0, p1);
        pk[nf][qc][1] = packbf2(p2, p3);
      }
#pragma unroll
      for (int f = 0; f < 8; ++f)
#pragma unroll
        for (int r = 0; r < 4; ++r) o[f][qc][r] *= sf;
    }

    // O^T += V^T P^T via 16x16x16: A = V^T[h][kv] (shared across qc), B = P^T
    __builtin_amdgcn_s_setprio(1);
#pragma unroll
    for (int nf = 0; nf < 4; ++nf) {
      const unsigned b00 = pk[nf][0][0], b01 = pk[nf][0][1];
      const unsigned b10 = pk[nf][1][0], b11 = pk[nf][1][1];
      const short* vrow = &Vp[kv0 + nf * 16 + rg * 4];
#pragma unroll
      for (int hf = 0; hf < 8; ++hf) {
        const unsigned* vp = (const unsigned*)&vrow[(size_t)(hf * 16 + cg) * T_];
        unsigned v0 = vp[0], v1 = vp[1];
        o[hf][0] = mfma16(v0, v1, b00, b01, o[hf][0]);
        o[hf][1] = mfma16(v0, v1, b10, b11, o[hf][1]);
      }
    }
    __builtin_amdgcn_s_setprio(0);
  }

  // reduce l across rg groups (same q); m already row-uniform
#pragma unroll
  for (int qc = 0; qc < 2; ++qc) {
    lsum[qc] += __shfl_xor(lsum[qc], 16);
    lsum[qc] += __shfl_xor(lsum[qc], 32);
  }
  if (lane < 16) {
#pragma unroll
    for (int qc = 0; qc < 2; ++qc) {
      Mml[wv][qc * 16 + lane] = m[qc];
      Lml[wv][qc * 16 + lane] = lsum[qc];
    }
  }
  // park partial O^T in LDS as [q][h] (f32x4 stores, padded stride)
#pragma unroll
  for (int hf = 0; hf < 8; ++hf)
#pragma unroll
    for (int qc = 0; qc < 2; ++qc)
      *(f32x4*)&OC[wv][(qc * 16 + cg) * OCW + hf * 16 + rg * 4] = o[hf][qc];
  __syncthreads();

  // flash-combine the 4 partials, normalize, store fp32 coalesced
  for (int i = tid; i < 32 * 128; i += 256) {
    int row = i >> 7, col = i & 127;
    float m0v = Mml[0][row], m1v = Mml[1][row], m2v = Mml[2][row], m3v = Mml[3][row];
    float ms = fmaxf(fmaxf(m0v, m1v), fmaxf(m2v, m3v));
    float accv = 0.f, lacc = 0.f;
#pragma unroll
    for (int w = 0; w < 4; ++w) {
      float sc = exp2f(Mml[w][row] - ms);
      lacc += sc * Lml[w][row];
      accv += sc * OC[w][row * OCW + col];
    }
    out[(size_t)(b * T_ + q0 + row) * H_ + col] = accv / lacc;
  }
}

extern "C" void kernel_launch(void* const* d_in, const int* in_sizes, int n_in,
                              void* d_out, int out_size, void* d_ws, size_t ws_size,
                              hipStream_t stream) {
  const float* x  = (const float*)d_in[0];
  const float* Wq = (const float*)d_in[1];
  const float* Wk = (const float*)d_in[2];
  const float* Wv = (const float*)d_in[3];
  float* out = (float*)d_out;
  char* ws = (char*)d_ws;

  short* Wt = (short*)(ws);                          // 768 KB
  short* Qb = (short*)(ws + ((size_t)1 << 20));      // 4 MB
  short* Kb = (short*)(ws + ((size_t)5 << 20));      // 4 MB
  short* VT = (short*)(ws + ((size_t)9 << 20));      // 4 MB  (total 13 MB)

  prep_wt<<<dim3(48), dim3(256), 0, stream>>>(Wq, Wk, Wv, Wt);
  proj<<<dim3(512), dim3(256), 0, stream>>>(x, Wt, Qb, Kb, VT);
  attn<<<dim3(512), dim3(256), 0, stream>>>(Qb, Kb, VT, out);
}

// Round 6
// 86.439 us; speedup vs baseline: 2.2884x; 1.4935x over previous
//
#include <hip/hip_runtime.h>

// Fused causal attention head: B=8, T=2048, C=1024, H=128 (fp32 in/out).
//   q,k,v = x@W{q,k,v};  out = softmax(tril(q k^T * C^-0.5)) @ v
// Round-6 key idea: ALL intermediate tensors (Wtf, Qf, Kf, Vf) are stored in
// MFMA-fragment-major order, so every hot load in proj/attn is a fully
// coalesced `base + lane*16B` (or 8B) read instead of a 16-row gather
// (rounds 1-5 were front-end bound on address divergence: 16 L1 lines/load).
//   QK-frag layout (for Q, K, Wt): frag(t16, k32) = 1KB contiguous;
//     idx(t,h) = ((t>>4)*NK + (h>>5))*512 + ((h>>3)&3)*128 + (t&15)*8 + (h&7)
//   V-frag layout (PV A-operand): frag(t16, h16) = 512B contiguous;
//     idx(h,t) = ((t>>4)*8 + (h>>4))*256 + (h&15)*16 + (t&15)
// proj: BM=64, BK=128, 8 waves (wave = 64r x 48c, M_rep=4), dbuf LDS via
//       global_load_lds w16 (pre-swizzled source). grid 256.
// attn: flash, swapped QK^T, QBLK=32, in-register P, kv-split across 4 waves,
//       LDS flash-combine. grid 512.
// Workspace (~13 MB): [0,768K) Wtf  [1M,5M) Qf  [5M,9M) Kf  [9M,13M) Vf

#define B_ 8
#define T_ 2048
#define C_ 1024
#define H_ 128

typedef __attribute__((ext_vector_type(4))) float  f32x4;
typedef __attribute__((ext_vector_type(8))) __bf16 bf16x8;
typedef __attribute__((ext_vector_type(4))) __bf16 bf16x4;
typedef __attribute__((ext_vector_type(4))) short  short4v;

#define QSCALE (0.03125f * 1.44269504088896340736f)  // C^-0.5 * log2(e)

static __device__ __forceinline__ short f2bf(float f) {
  union { __bf16 b; short s; } u;
  u.b = (__bf16)f;
  return u.s;
}

static __device__ __forceinline__ unsigned packbf2(float lo, float hi) {
  union { __bf16 b; unsigned short s; } a, c;
  a.b = (__bf16)lo; c.b = (__bf16)hi;
  return (unsigned)a.s | ((unsigned)c.s << 16);
}

// fragment-major index helpers (see header comment)
static __device__ __forceinline__ size_t qk_idx(int t, int h, int nk) {
  return ((size_t)((t >> 4) * nk + (h >> 5)) << 9) + (((h >> 3) & 3) << 7)
       + ((t & 15) << 3) + (h & 7);
}
static __device__ __forceinline__ size_t v_idx(int h, int t) {
  return ((size_t)((t >> 4) * 8 + (h >> 4)) << 8) + ((h & 15) << 4) + (t & 15);
}

// D = A(16x16) * B(16x16) + C, bf16, K=16.
// A-frag: A[row=lane&15][k=(lane>>4)*4+j]; B-frag: B[k=(lane>>4)*4+j][col=lane&15].
static __device__ __forceinline__ f32x4 mfma16(unsigned a0, unsigned a1,
                                               unsigned b0, unsigned b1, f32x4 c) {
#if __has_builtin(__builtin_amdgcn_mfma_f32_16x16x16_bf16)
  union { unsigned u[2]; bf16x4 v; } ua, ub;
  ua.u[0] = a0; ua.u[1] = a1; ub.u[0] = b0; ub.u[1] = b1;
  return __builtin_amdgcn_mfma_f32_16x16x16_bf16(ua.v, ub.v, c, 0, 0, 0);
#elif __has_builtin(__builtin_amdgcn_mfma_f32_16x16x16bf16_1k)
  union { unsigned u[2]; short4v v; } ua, ub;
  ua.u[0] = a0; ua.u[1] = a1; ub.u[0] = b0; ub.u[1] = b1;
  return __builtin_amdgcn_mfma_f32_16x16x16bf16_1k(ua.v, ub.v, c, 0, 0, 0);
#else
  union { unsigned u[2]; short4v v; } ua, ub;
  ua.u[0] = a0; ua.u[1] = a1; ub.u[0] = b0; ub.u[1] = b1;
  f32x4 d = c;
  asm volatile("v_mfma_f32_16x16x16_bf16 %0, %1, %2, %0"
               : "+v"(d) : "v"(ua.v), "v"(ub.v));
  return d;
#endif
}

static __device__ __forceinline__ void gload_lds16(const void* g, void* l) {
  __builtin_amdgcn_global_load_lds(
      (const __attribute__((address_space(1))) unsigned int*)g,
      (__attribute__((address_space(3))) unsigned int*)l, 16, 0, 0);
}

// ---------------- prep: Wtf frag-major; Wq pre-scaled by QSCALE --------------------
// grid 48 = 3 matrices x 16 k-chunks of 64. Coalesced reads via LDS transpose;
// writes are scattered 2B into fragment layout (tiny kernel, cost irrelevant).
__global__ void prep_wt(const float* __restrict__ Wq, const float* __restrict__ Wk,
                        const float* __restrict__ Wv, short* __restrict__ Wtf) {
  __shared__ float L[64 * 129];
  const int mtx = blockIdx.x >> 4, kc = blockIdx.x & 15;
  const int k0 = kc * 64;
  const float* W = (mtx == 0) ? Wq : (mtx == 1 ? Wk : Wv);
  const float s = (mtx == 0) ? QSCALE : 1.0f;
  for (int i = threadIdx.x; i < 64 * 128; i += 256) {
    int kk = i >> 7, c = i & 127;
    L[kk * 129 + c] = W[(size_t)(k0 + kk) * H_ + c] * s;
  }
  __syncthreads();
  for (int i = threadIdx.x; i < 128 * 64; i += 256) {
    int n = i >> 6, kk = i & 63;
    int n_g = mtx * 128 + n, k_g = k0 + kk;
    // Wtf "t" dim = output col n (384 wide -> nk = 1024/32 = 32 k-frags per row)
    Wtf[qk_idx(n_g, k_g, 32)] = f2bf(L[kk * 129 + n]);
  }
}

// ---------------- proj: BM=64 x 384 cols, BK=128, dbuf LDS, 8 waves, grid 256 -----
// wave wv: 64 rows x cols [wv*48, wv*48+48). 12 MFMA per k-step of 32; B-frag
// loads fully coalesced from Wtf.
__global__ __launch_bounds__(512) void proj(const float* __restrict__ x,
                                            const short* __restrict__ Wtf,
                                            short* __restrict__ Qf,
                                            short* __restrict__ Kf,
                                            short* __restrict__ Vf) {
  __shared__ __align__(16) float At[2][64 * 128];  // 2 x 32 KB
  const int tid = threadIdx.x, lane = tid & 63, wv = tid >> 6;
  const int cg = lane & 15, rg = lane >> 4;
  const int lane8 = lane << 3;
  const int m0 = blockIdx.x * 64;
  const float* xblk = x + (size_t)m0 * C_;

  f32x4 acc[4][3];
#pragma unroll
  for (int i = 0; i < 4; ++i)
#pragma unroll
    for (int j = 0; j < 3; ++j) {
      f32x4 z = {0.f, 0.f, 0.f, 0.f};
      acc[i][j] = z;
    }

  // stage BK-tile kt into buffer bf: 2048 slots of 16B, dest linear,
  // source pre-swizzled (slot ^= row&7) so swizzled ds_read is conflict-free.
#define STAGE(bf, kt)                                                          \
  {                                                                            \
    int k0s = (kt) * 128;                                                      \
    _Pragma("unroll") for (int it = 0; it < 4; ++it) {                         \
      int slotbase = it * 512 + wv * 64; /* wave-uniform */                    \
      int slot = slotbase + lane;                                              \
      int r = slot >> 5, s5 = slot & 31;                                       \
      gload_lds16(xblk + (size_t)r * C_ + k0s + ((s5 ^ (r & 7)) << 2),         \
                  &At[bf][slotbase * 4]);                                      \
    }                                                                          \
  }

  STAGE(0, 0);
  __syncthreads();

  for (int kt = 0; kt < 8; ++kt) {
    const int cur = kt & 1;
    if (kt < 7) STAGE(cur ^ 1, kt + 1);

#pragma unroll
    for (int ks = 0; ks < 4; ++ks) {
      bf16x8 af[4];
#pragma unroll
      for (int fm = 0; fm < 4; ++fm) {
        int r = fm * 16 + cg;
        int s0 = ks * 8 + rg * 2;
        f32x4 a0 = *(const f32x4*)&At[cur][r * 128 + (((s0    ) ^ (r & 7)) << 2)];
        f32x4 a1 = *(const f32x4*)&At[cur][r * 128 + (((s0 + 1) ^ (r & 7)) << 2)];
        bf16x8 tv;
        tv[0] = (__bf16)a0[0]; tv[1] = (__bf16)a0[1];
        tv[2] = (__bf16)a0[2]; tv[3] = (__bf16)a0[3];
        tv[4] = (__bf16)a1[0]; tv[5] = (__bf16)a1[1];
        tv[6] = (__bf16)a1[2]; tv[7] = (__bf16)a1[3];
        af[fm] = tv;
      }
#pragma unroll
      for (int nf = 0; nf < 3; ++nf) {
        // coalesced B-frag: 1KB contiguous, lane*16B
        bf16x8 bfr = *(const bf16x8*)&Wtf[((size_t)((wv * 3 + nf) * 32 + kt * 4 + ks) << 9) + lane8];
#pragma unroll
        for (int fm = 0; fm < 4; ++fm)
          acc[fm][nf] = __builtin_amdgcn_mfma_f32_16x16x32_bf16(af[fm], bfr, acc[fm][nf], 0, 0, 0);
      }
    }
    __syncthreads();  // staged(kt+1) complete; all reads of cur done before overwrite
  }
#undef STAGE

  // epilogue: D frag row=(lane>>4)*4+r, col=lane&15; scatter into frag layouts
#pragma unroll
  for (int fm = 0; fm < 4; ++fm) {
#pragma unroll
    for (int nf = 0; nf < 3; ++nf) {
      int n = wv * 48 + nf * 16 + cg;
      int rowm = m0 + fm * 16 + rg * 4;
      size_t boff = (size_t)(rowm >> 11) << 18;   // batch * 2048*128
      f32x4 v = acc[fm][nf];
      if (n < 128) {
#pragma unroll
        for (int r = 0; r < 4; ++r)
          Qf[boff + qk_idx((rowm + r) & 2047, n, 4)] = f2bf(v[r]);
      } else if (n < 256) {
#pragma unroll
        for (int r = 0; r < 4; ++r)
          Kf[boff + qk_idx((rowm + r) & 2047, n - 128, 4)] = f2bf(v[r]);
      } else {
#pragma unroll
        for (int r = 0; r < 4; ++r)
          Vf[boff + v_idx(n - 256, (rowm + r) & 2047)] = f2bf(v[r]);
      }
    }
  }
}

// ---------------- attn: QBLK=32, swapped QK^T, in-register softmax/P --------------
// grid 512: bid&7 = batch (XCD-local K/V), 63-(bid>>3) = q-group (largest first).
// 4 waves share 32 q-rows, split kv range; flash-combine partials in LDS.
// All K/V/Q loads are coalesced fragment reads.
#define OCW 132  // 128 + 4 pad
__global__ __launch_bounds__(256) void attn(const short* __restrict__ Qf,
                                            const short* __restrict__ Kf,
                                            const short* __restrict__ Vf,
                                            float* __restrict__ out) {
  __shared__ __align__(16) float OC[4][32 * OCW];   // 67.6 KB
  __shared__ float Mml[4][32], Lml[4][32];
  const int tid = threadIdx.x, lane = tid & 63, wv = tid >> 6;
  const int cg = lane & 15, rg = lane >> 4;
  const int lane8 = lane << 3;
  const int bid = blockIdx.x;
  const int b = bid & 7;
  const int qg = 63 - (bid >> 3);
  const int q0 = qg << 5;
  const int NT = (q0 + 95) >> 6;         // ceil((q0+32)/64) kv-tiles of 64
  const int SPW = (NT + 3) >> 2;
  const int t0 = wv * SPW;
  const int t1 = (t0 + SPW < NT) ? (t0 + SPW) : NT;

  const short* Qp = Qf + ((size_t)b << 18);
  const short* Kp = Kf + ((size_t)b << 18);
  const short* Vp = Vf + ((size_t)b << 18);
  const float NEG_INF = -__builtin_inff();

  // Q frags (B-operand for swapped QK^T): coalesced frag reads
  bf16x8 qf[2][4];
#pragma unroll
  for (int qc = 0; qc < 2; ++qc)
#pragma unroll
    for (int ks = 0; ks < 4; ++ks)
      qf[qc][ks] = *(const bf16x8*)&Qp[((size_t)(((q0 >> 4) + qc) * 4 + ks) << 9) + lane8];

  f32x4 o[8][2];                         // O^T: o[hf][qc][r] = O[q][h=hf*16+rg*4+r]
#pragma unroll
  for (int f = 0; f < 8; ++f)
#pragma unroll
    for (int qc = 0; qc < 2; ++qc) { f32x4 z = {0.f, 0.f, 0.f, 0.f}; o[f][qc] = z; }
  float m[2] = {NEG_INF, NEG_INF}, lsum[2] = {0.0f, 0.0f};

  for (int t = t0; t < t1; ++t) {
    const int kv0 = t * 64;
    const short* ktile = Kp + (size_t)t * 8192;   // 16KB contiguous K-tile
    const short* vtile = Vp + (size_t)t * 8192;   // 16KB contiguous V-tile

    // batch all 16 K frag loads (each: lane*16B coalesced 1KB)
    bf16x8 kf[4][4];
#pragma unroll
    for (int nf = 0; nf < 4; ++nf)
#pragma unroll
      for (int ks = 0; ks < 4; ++ks)
        kf[nf][ks] = *(const bf16x8*)&ktile[((nf * 4 + ks) << 9) + lane8];

    f32x4 s[4][2];
#pragma unroll
    for (int nf = 0; nf < 4; ++nf)
#pragma unroll
      for (int qc = 0; qc < 2; ++qc) { f32x4 z = {0.f, 0.f, 0.f, 0.f}; s[nf][qc] = z; }

    // S^T = K Q^T: s[nf][qc][r] = S[q=q0+qc*16+cg][kv = kv0+nf*16+rg*4+r]
    __builtin_amdgcn_s_setprio(1);
#pragma unroll
    for (int nf = 0; nf < 4; ++nf)
#pragma unroll
      for (int ks = 0; ks < 4; ++ks) {
        s[nf][0] = __builtin_amdgcn_mfma_f32_16x16x32_bf16(kf[nf][ks], qf[0][ks], s[nf][0], 0, 0, 0);
        s[nf][1] = __builtin_amdgcn_mfma_f32_16x16x32_bf16(kf[nf][ks], qf[1][ks], s[nf][1], 0, 0, 0);
      }
    __builtin_amdgcn_s_setprio(0);

    // causal mask (only the globally-last tile straddles the diagonal)
    if (t == NT - 1) {
#pragma unroll
      for (int nf = 0; nf < 4; ++nf)
#pragma unroll
        for (int qc = 0; qc < 2; ++qc)
#pragma unroll
          for (int r = 0; r < 4; ++r)
            if (kv0 + nf * 16 + rg * 4 + r > q0 + qc * 16 + cg) s[nf][qc][r] = NEG_INF;
    }

    // online softmax (exp2 domain), per q-col group
    unsigned pk[4][2][2];
#pragma unroll
    for (int qc = 0; qc < 2; ++qc) {
      float pm = s[0][qc][0];
#pragma unroll
      for (int nf = 0; nf < 4; ++nf)
#pragma unroll
        for (int r = 0; r < 4; ++r) pm = fmaxf(pm, s[nf][qc][r]);
      pm = fmaxf(pm, __shfl_xor(pm, 16));
      pm = fmaxf(pm, __shfl_xor(pm, 32));   // full row max (finite: kv0 <= q always)
      float mn = fmaxf(m[qc], pm);
      float sf = exp2f(m[qc] - mn);         // first tile: exp2(-inf) = 0
      m[qc] = mn;
      lsum[qc] *= sf;
#pragma unroll
      for (int nf = 0; nf < 4; ++nf) {
        float p0 = exp2f(s[nf][qc][0] - mn), p1 = exp2f(s[nf][qc][1] - mn);
        float p2 = exp2f(s[nf][qc][2] - mn), p3 = exp2f(s[nf][qc][3] - mn);
        lsum[qc] += (p0 + p1) + (p2 + p3);
        pk[nf][qc][0] = packbf2(p0, p1);
        pk[nf][qc][1] = packbf2(p2, p3);
      }
#pragma unroll
      for (int f = 0; f < 8; ++f)
#pragma unroll
        for (int r = 0; r < 4; ++r) o[f][qc][r] *= sf;
    }

    // O^T += V^T P^T via 16x16x16: A = V^T frag (coalesced 8B/lane), B = P^T (regs)
    __builtin_amdgcn_s_setprio(1);
#pragma unroll
    for (int nf = 0; nf < 4; ++nf) {
      const unsigned b00 = pk[nf][0][0], b01 = pk[nf][0][1];
      const unsigned b10 = pk[nf][1][0], b11 = pk[nf][1][1];
#pragma unroll
      for (int hf = 0; hf < 8; ++hf) {
        const unsigned* vp = (const unsigned*)&vtile[((nf * 8 + hf) << 8) + (cg << 4) + (rg << 2)];
        unsigned v0 = vp[0], v1 = vp[1];
        o[hf][0] = mfma16(v0, v1, b00, b01, o[hf][0]);
        o[hf][1] = mfma16(v0, v1, b10, b11, o[hf][1]);
      }
    }
    __builtin_amdgcn_s_setprio(0);
  }

  // reduce l across rg groups (same q); m already row-uniform
#pragma unroll
  for (int qc = 0; qc < 2; ++qc) {
    lsum[qc] += __shfl_xor(lsum[qc], 16);
    lsum[qc] += __shfl_xor(lsum[qc], 32);
  }
  if (lane < 16) {
#pragma unroll
    for (int qc = 0; qc < 2; ++qc) {
      Mml[wv][qc * 16 + lane] = m[qc];
      Lml[wv][qc * 16 + lane] = lsum[qc];
    }
  }
  // park partial O^T in LDS as [q][h] (f32x4 stores, padded stride)
#pragma unroll
  for (int hf = 0; hf < 8; ++hf)
#pragma unroll
    for (int qc = 0; qc < 2; ++qc)
      *(f32x4*)&OC[wv][(qc * 16 + cg) * OCW + hf * 16 + rg * 4] = o[hf][qc];
  __syncthreads();

  // flash-combine the 4 partials, normalize, store fp32 coalesced
  for (int i = tid; i < 32 * 128; i += 256) {
    int row = i >> 7, col = i & 127;
    float m0v = Mml[0][row], m1v = Mml[1][row], m2v = Mml[2][row], m3v = Mml[3][row];
    float ms = fmaxf(fmaxf(m0v, m1v), fmaxf(m2v, m3v));
    float accv = 0.f, lacc = 0.f;
#pragma unroll
    for (int w = 0; w < 4; ++w) {
      float sc = exp2f(Mml[w][row] - ms);
      lacc += sc * Lml[w][row];
      accv += sc * OC[w][row * OCW + col];
    }
    out[(size_t)(b * T_ + q0 + row) * H_ + col] = accv / lacc;
  }
}

extern "C" void kernel_launch(void* const* d_in, const int* in_sizes, int n_in,
                              void* d_out, int out_size, void* d_ws, size_t ws_size,
                              hipStream_t stream) {
  const float* x  = (const float*)d_in[0];
  const float* Wq = (const float*)d_in[1];
  const float* Wk = (const float*)d_in[2];
  const float* Wv = (const float*)d_in[3];
  float* out = (float*)d_out;
  char* ws = (char*)d_ws;

  short* Wtf = (short*)(ws);                         // 768 KB
  short* Qf  = (short*)(ws + ((size_t)1 << 20));     // 4 MB
  short* Kf  = (short*)(ws + ((size_t)5 << 20));     // 4 MB
  short* Vf  = (short*)(ws + ((size_t)9 << 20));     // 4 MB  (total 13 MB)

  prep_wt<<<dim3(48), dim3(256), 0, stream>>>(Wq, Wk, Wv, Wtf);
  proj<<<dim3(256), dim3(512), 0, stream>>>(x, Wtf, Qf, Kf, Vf);
  attn<<<dim3(512), dim3(256), 0, stream>>>(Qf, Kf, Vf, out);
}

// Round 7
// 75.633 us; speedup vs baseline: 2.6153x; 1.1429x over previous
//
#include <hip/hip_runtime.h>

// Fused causal attention head: B=8, T=2048, C=1024, H=128 (fp32 in/out).
//   q,k,v = x@W{q,k,v};  out = softmax(tril(q k^T * C^-0.5)) @ v
// All intermediates (Wtf, Qf, Kf, Vf) are MFMA-fragment-major so every hot load
// is a coalesced `base + lane*16B` read (round-6 win).
//   QK-frag layout: frag(t16, k32) = 1KB contiguous;
//     idx(t,h) = ((t>>4)*NK + (h>>5))*512 + ((h>>3)&3)*128 + (t&15)*8 + (h&7)
//   V-frag layout: frag(t16, h16) = 512B contiguous;
//     idx(h,t) = ((t>>4)*8 + (h>>4))*256 + (h&15)*16 + (t&15)
// Round-7:
//   proj: bf16 LDS A-tile (1 ds_read_b128 = 1 frag, cvt at staging only),
//         reg-staged dbuf w/ single barrier per kt, N-split 192 -> grid 512.
//   attn: K-tile software pipeline into the SAME kf regs (loads issued after
//         the S-cluster, hidden under softmax+PV), V nf0 prefetch.
// Workspace (~13 MB): [0,768K) Wtf  [1M,5M) Qf  [5M,9M) Kf  [9M,13M) Vf

#define B_ 8
#define T_ 2048
#define C_ 1024
#define H_ 128

typedef __attribute__((ext_vector_type(4))) float  f32x4;
typedef __attribute__((ext_vector_type(8))) __bf16 bf16x8;
typedef __attribute__((ext_vector_type(4))) __bf16 bf16x4;
typedef __attribute__((ext_vector_type(4))) short  short4v;

#define QSCALE (0.03125f * 1.44269504088896340736f)  // C^-0.5 * log2(e)

static __device__ __forceinline__ short f2bf(float f) {
  union { __bf16 b; short s; } u;
  u.b = (__bf16)f;
  return u.s;
}

static __device__ __forceinline__ unsigned packbf2(float lo, float hi) {
  union { __bf16 b; unsigned short s; } a, c;
  a.b = (__bf16)lo; c.b = (__bf16)hi;
  return (unsigned)a.s | ((unsigned)c.s << 16);
}

// fragment-major index helpers
static __device__ __forceinline__ size_t qk_idx(int t, int h, int nk) {
  return ((size_t)((t >> 4) * nk + (h >> 5)) << 9) + (((h >> 3) & 3) << 7)
       + ((t & 15) << 3) + (h & 7);
}
static __device__ __forceinline__ size_t v_idx(int h, int t) {
  return ((size_t)((t >> 4) * 8 + (h >> 4)) << 8) + ((h & 15) << 4) + (t & 15);
}

// D = A(16x16) * B(16x16) + C, bf16, K=16.
static __device__ __forceinline__ f32x4 mfma16(unsigned a0, unsigned a1,
                                               unsigned b0, unsigned b1, f32x4 c) {
#if __has_builtin(__builtin_amdgcn_mfma_f32_16x16x16_bf16)
  union { unsigned u[2]; bf16x4 v; } ua, ub;
  ua.u[0] = a0; ua.u[1] = a1; ub.u[0] = b0; ub.u[1] = b1;
  return __builtin_amdgcn_mfma_f32_16x16x16_bf16(ua.v, ub.v, c, 0, 0, 0);
#elif __has_builtin(__builtin_amdgcn_mfma_f32_16x16x16bf16_1k)
  union { unsigned u[2]; short4v v; } ua, ub;
  ua.u[0] = a0; ua.u[1] = a1; ub.u[0] = b0; ub.u[1] = b1;
  return __builtin_amdgcn_mfma_f32_16x16x16bf16_1k(ua.v, ub.v, c, 0, 0, 0);
#else
  union { unsigned u[2]; short4v v; } ua, ub;
  ua.u[0] = a0; ua.u[1] = a1; ub.u[0] = b0; ub.u[1] = b1;
  f32x4 d = c;
  asm volatile("v_mfma_f32_16x16x16_bf16 %0, %1, %2, %0"
               : "+v"(d) : "v"(ua.v), "v"(ub.v));
  return d;
#endif
}

// ---------------- prep: Wtf frag-major; Wq pre-scaled by QSCALE -------------------
__global__ void prep_wt(const float* __restrict__ Wq, const float* __restrict__ Wk,
                        const float* __restrict__ Wv, short* __restrict__ Wtf) {
  __shared__ float L[64 * 129];
  const int mtx = blockIdx.x >> 4, kc = blockIdx.x & 15;
  const int k0 = kc * 64;
  const float* W = (mtx == 0) ? Wq : (mtx == 1 ? Wk : Wv);
  const float s = (mtx == 0) ? QSCALE : 1.0f;
  for (int i = threadIdx.x; i < 64 * 128; i += 256) {
    int kk = i >> 7, c = i & 127;
    L[kk * 129 + c] = W[(size_t)(k0 + kk) * H_ + c] * s;
  }
  __syncthreads();
  for (int i = threadIdx.x; i < 128 * 64; i += 256) {
    int n = i >> 6, kk = i & 63;
    Wtf[qk_idx(mtx * 128 + n, k0 + kk, 32)] = f2bf(L[kk * 129 + n]);
  }
}

// ---------------- proj: BM=64 x BN=192, BK=128, bf16 dbuf LDS, 4 waves, grid 512 --
// bid: xcd = bid&7, g = (bid&7)*64 + (bid>>3); mb = g>>1, bn = g&1 (n-halves of
// the same rows co-located per XCD for x L2 reuse).
// wave wv: 64 rows x 48 cols (M_rep=4, N_rep=3) -> 48 MFMA per kt.
__global__ __launch_bounds__(256) void proj(const float* __restrict__ x,
                                            const short* __restrict__ Wtf,
                                            short* __restrict__ Qf,
                                            short* __restrict__ Kf,
                                            short* __restrict__ Vf) {
  __shared__ __align__(16) short At[2][64 * 128];  // bf16 tiles, 16 KB each
  const int tid = threadIdx.x, lane = tid & 63, wv = tid >> 6;
  const int cg = lane & 15, rg = lane >> 4;
  const int lane8 = lane << 3;
  const int g = (blockIdx.x & 7) * 64 + (blockIdx.x >> 3);
  const int mb = g >> 1, bn = g & 1;
  const int m0 = mb * 64;
  const int nfrag0 = bn * 12 + wv * 3;
  const float* xblk = x + (size_t)m0 * C_;

  f32x4 acc[4][3];
#pragma unroll
  for (int i = 0; i < 4; ++i)
#pragma unroll
    for (int j = 0; j < 3; ++j) {
      f32x4 z = {0.f, 0.f, 0.f, 0.f};
      acc[i][j] = z;
    }

  f32x4 ldr[4][2];  // staging regs: 4 slots x 8 floats

  // issue global loads for BK-tile kt (8 floats per slot, 4 slots/thread, coalesced)
#define PLOAD(kt)                                                              \
  { _Pragma("unroll") for (int it = 0; it < 4; ++it) {                         \
      int ls = it * 256 + tid; int r = ls >> 4, sc = ls & 15;                  \
      const float* p = xblk + (size_t)r * C_ + (kt) * 128 + sc * 8;            \
      ldr[it][0] = *(const f32x4*)p; ldr[it][1] = *(const f32x4*)(p + 4);      \
  } }

  // cvt + write staged regs to LDS buffer (16B slots, XOR-swizzled: slot ^= r&7)
#define PWRITE(bf)                                                             \
  { _Pragma("unroll") for (int it = 0; it < 4; ++it) {                         \
      int ls = it * 256 + tid; int r = ls >> 4, sc = ls & 15;                  \
      bf16x8 tv;                                                               \
      tv[0] = (__bf16)ldr[it][0][0]; tv[1] = (__bf16)ldr[it][0][1];            \
      tv[2] = (__bf16)ldr[it][0][2]; tv[3] = (__bf16)ldr[it][0][3];            \
      tv[4] = (__bf16)ldr[it][1][0]; tv[5] = (__bf16)ldr[it][1][1];            \
      tv[6] = (__bf16)ldr[it][1][2]; tv[7] = (__bf16)ldr[it][1][3];            \
      *(bf16x8*)&At[bf][r * 128 + ((sc ^ (r & 7)) << 3)] = tv;                 \
  } }

  PLOAD(0);
  PWRITE(0);
  __syncthreads();

  for (int kt = 0; kt < 8; ++kt) {
    const int cur = kt & 1;
    if (kt < 7) PLOAD(kt + 1);   // T14: issue next-tile loads before compute

#pragma unroll
    for (int ks = 0; ks < 4; ++ks) {
      bf16x8 af[4];
#pragma unroll
      for (int fm = 0; fm < 4; ++fm) {
        int r = fm * 16 + cg;
        int slot = (ks * 4 + rg) ^ (r & 7);
        af[fm] = *(const bf16x8*)&At[cur][r * 128 + (slot << 3)];
      }
#pragma unroll
      for (int nf = 0; nf < 3; ++nf) {
        bf16x8 bfr = *(const bf16x8*)&Wtf[((size_t)((nfrag0 + nf) * 32 + kt * 4 + ks) << 9) + lane8];
#pragma unroll
        for (int fm = 0; fm < 4; ++fm)
          acc[fm][nf] = __builtin_amdgcn_mfma_f32_16x16x32_bf16(af[fm], bfr, acc[fm][nf], 0, 0, 0);
      }
    }
    if (kt < 7) PWRITE(cur ^ 1);  // write target != read buffer: no barrier needed
    __syncthreads();              // one barrier per kt
  }
#undef PLOAD
#undef PWRITE

  // epilogue: D frag row=(lane>>4)*4+r, col=lane&15; scatter into frag layouts
#pragma unroll
  for (int fm = 0; fm < 4; ++fm) {
#pragma unroll
    for (int nf = 0; nf < 3; ++nf) {
      int n = (nfrag0 + nf) * 16 + cg;
      int rowm = m0 + fm * 16 + rg * 4;
      size_t boff = (size_t)(rowm >> 11) << 18;   // batch * 2048*128
      f32x4 v = acc[fm][nf];
      if (n < 128) {
#pragma unroll
        for (int r = 0; r < 4; ++r)
          Qf[boff + qk_idx((rowm + r) & 2047, n, 4)] = f2bf(v[r]);
      } else if (n < 256) {
#pragma unroll
        for (int r = 0; r < 4; ++r)
          Kf[boff + qk_idx((rowm + r) & 2047, n - 128, 4)] = f2bf(v[r]);
      } else {
#pragma unroll
        for (int r = 0; r < 4; ++r)
          Vf[boff + v_idx(n - 256, (rowm + r) & 2047)] = f2bf(v[r]);
      }
    }
  }
}

// ---------------- attn: QBLK=32, swapped QK^T, K software-pipeline ----------------
// grid 512: bid&7 = batch (XCD-local K/V), 63-(bid>>3) = q-group (largest first).
// 4 waves share 32 q-rows, split kv range; flash-combine partials in LDS.
#define OCW 132  // 128 + 4 pad
__global__ __launch_bounds__(256) void attn(const short* __restrict__ Qf,
                                            const short* __restrict__ Kf,
                                            const short* __restrict__ Vf,
                                            float* __restrict__ out) {
  __shared__ __align__(16) float OC[4][32 * OCW];   // 67.6 KB
  __shared__ float Mml[4][32], Lml[4][32];
  const int tid = threadIdx.x, lane = tid & 63, wv = tid >> 6;
  const int cg = lane & 15, rg = lane >> 4;
  const int lane8 = lane << 3;
  const int bid = blockIdx.x;
  const int b = bid & 7;
  const int qg = 63 - (bid >> 3);
  const int q0 = qg << 5;
  const int NT = (q0 + 95) >> 6;         // ceil((q0+32)/64) kv-tiles of 64
  const int SPW = (NT + 3) >> 2;
  const int t0 = wv * SPW;
  const int t1 = (t0 + SPW < NT) ? (t0 + SPW) : NT;

  const short* Qp = Qf + ((size_t)b << 18);
  const short* Kp = Kf + ((size_t)b << 18);
  const short* Vp = Vf + ((size_t)b << 18);
  const float NEG_INF = -__builtin_inff();

  // Q frags (B-operand for swapped QK^T): coalesced frag reads
  bf16x8 qf[2][4];
#pragma unroll
  for (int qc = 0; qc < 2; ++qc)
#pragma unroll
    for (int ks = 0; ks < 4; ++ks)
      qf[qc][ks] = *(const bf16x8*)&Qp[((size_t)(((q0 >> 4) + qc) * 4 + ks) << 9) + lane8];

  f32x4 o[8][2];                         // O^T: o[hf][qc][r] = O[q][h=hf*16+rg*4+r]
#pragma unroll
  for (int f = 0; f < 8; ++f)
#pragma unroll
    for (int qc = 0; qc < 2; ++qc) { f32x4 z = {0.f, 0.f, 0.f, 0.f}; o[f][qc] = z; }
  float m[2] = {NEG_INF, NEG_INF}, lsum[2] = {0.0f, 0.0f};

  bf16x8 kf[4][4];
#define LOADK(t_)                                                              \
  { const short* ktp = Kp + (size_t)(t_) * 8192;                               \
    _Pragma("unroll") for (int nf_ = 0; nf_ < 4; ++nf_)                        \
    _Pragma("unroll") for (int ks_ = 0; ks_ < 4; ++ks_)                        \
      kf[nf_][ks_] = *(const bf16x8*)&ktp[((nf_ * 4 + ks_) << 9) + lane8]; }

  if (t0 < t1) LOADK(t0);

  for (int t = t0; t < t1; ++t) {
    const int kv0 = t * 64;
    const short* vtile = Vp + (size_t)t * 8192;

    f32x4 s[4][2];
#pragma unroll
    for (int nf = 0; nf < 4; ++nf)
#pragma unroll
      for (int qc = 0; qc < 2; ++qc) { f32x4 z = {0.f, 0.f, 0.f, 0.f}; s[nf][qc] = z; }

    // S^T = K Q^T: s[nf][qc][r] = S[q=q0+qc*16+cg][kv = kv0+nf*16+rg*4+r]
    __builtin_amdgcn_s_setprio(1);
#pragma unroll
    for (int nf = 0; nf < 4; ++nf)
#pragma unroll
      for (int ks = 0; ks < 4; ++ks) {
        s[nf][0] = __builtin_amdgcn_mfma_f32_16x16x32_bf16(kf[nf][ks], qf[0][ks], s[nf][0], 0, 0, 0);
        s[nf][1] = __builtin_amdgcn_mfma_f32_16x16x32_bf16(kf[nf][ks], qf[1][ks], s[nf][1], 0, 0, 0);
      }
    __builtin_amdgcn_s_setprio(0);

    // K software-pipeline: load NEXT tile into the same kf regs (dead after the
    // S-cluster issues); latency hides under softmax + PV below.
    if (t + 1 < t1) LOADK(t + 1);

    // V nf0 prefetch (hides the initial PV load stall under softmax)
    unsigned v0a[8], v0b[8];
#pragma unroll
    for (int hf = 0; hf < 8; ++hf) {
      const unsigned* vp = (const unsigned*)&vtile[(hf << 8) + (cg << 4) + (rg << 2)];
      v0a[hf] = vp[0]; v0b[hf] = vp[1];
    }

    // causal mask (only the globally-last tile straddles the diagonal)
    if (t == NT - 1) {
#pragma unroll
      for (int nf = 0; nf < 4; ++nf)
#pragma unroll
        for (int qc = 0; qc < 2; ++qc)
#pragma unroll
          for (int r = 0; r < 4; ++r)
            if (kv0 + nf * 16 + rg * 4 + r > q0 + qc * 16 + cg) s[nf][qc][r] = NEG_INF;
    }

    // online softmax (exp2 domain), per q-col group
    unsigned pk[4][2][2];
#pragma unroll
    for (int qc = 0; qc < 2; ++qc) {
      float pm = s[0][qc][0];
#pragma unroll
      for (int nf = 0; nf < 4; ++nf)
#pragma unroll
        for (int r = 0; r < 4; ++r) pm = fmaxf(pm, s[nf][qc][r]);
      pm = fmaxf(pm, __shfl_xor(pm, 16));
      pm = fmaxf(pm, __shfl_xor(pm, 32));   // full row max (finite: kv0 <= q always)
      float mn = fmaxf(m[qc], pm);
      float sf = exp2f(m[qc] - mn);         // first tile: exp2(-inf) = 0
      m[qc] = mn;
      lsum[qc] *= sf;
#pragma unroll
      for (int nf = 0; nf < 4; ++nf) {
        float p0 = exp2f(s[nf][qc][0] - mn), p1 = exp2f(s[nf][qc][1] - mn);
        float p2 = exp2f(s[nf][qc][2] - mn), p3 = exp2f(s[nf][qc][3] - mn);
        lsum[qc] += (p0 + p1) + (p2 + p3);
        pk[nf][qc][0] = packbf2(p0, p1);
        pk[nf][qc][1] = packbf2(p2, p3);
      }
#pragma unroll
      for (int f = 0; f < 8; ++f)
#pragma unroll
        for (int r = 0; r < 4; ++r) o[f][qc][r] *= sf;
    }

    // O^T += V^T P^T via 16x16x16: A = V^T frag (nf0 from regs), B = P^T (regs)
    __builtin_amdgcn_s_setprio(1);
#pragma unroll
    for (int hf = 0; hf < 8; ++hf) {
      o[hf][0] = mfma16(v0a[hf], v0b[hf], pk[0][0][0], pk[0][0][1], o[hf][0]);
      o[hf][1] = mfma16(v0a[hf], v0b[hf], pk[0][1][0], pk[0][1][1], o[hf][1]);
    }
#pragma unroll
    for (int nf = 1; nf < 4; ++nf) {
      const unsigned b00 = pk[nf][0][0], b01 = pk[nf][0][1];
      const unsigned b10 = pk[nf][1][0], b11 = pk[nf][1][1];
#pragma unroll
      for (int hf = 0; hf < 8; ++hf) {
        const unsigned* vp = (const unsigned*)&vtile[((nf * 8 + hf) << 8) + (cg << 4) + (rg << 2)];
        unsigned v0 = vp[0], v1 = vp[1];
        o[hf][0] = mfma16(v0, v1, b00, b01, o[hf][0]);
        o[hf][1] = mfma16(v0, v1, b10, b11, o[hf][1]);
      }
    }
    __builtin_amdgcn_s_setprio(0);
  }
#undef LOADK

  // reduce l across rg groups (same q); m already row-uniform
#pragma unroll
  for (int qc = 0; qc < 2; ++qc) {
    lsum[qc] += __shfl_xor(lsum[qc], 16);
    lsum[qc] += __shfl_xor(lsum[qc], 32);
  }
  if (lane < 16) {
#pragma unroll
    for (int qc = 0; qc < 2; ++qc) {
      Mml[wv][qc * 16 + lane] = m[qc];
      Lml[wv][qc * 16 + lane] = lsum[qc];
    }
  }
  // park partial O^T in LDS as [q][h] (f32x4 stores, padded stride)
#pragma unroll
  for (int hf = 0; hf < 8; ++hf)
#pragma unroll
    for (int qc = 0; qc < 2; ++qc)
      *(f32x4*)&OC[wv][(qc * 16 + cg) * OCW + hf * 16 + rg * 4] = o[hf][qc];
  __syncthreads();

  // flash-combine the 4 partials, normalize, store fp32 coalesced
  for (int i = tid; i < 32 * 128; i += 256) {
    int row = i >> 7, col = i & 127;
    float m0v = Mml[0][row], m1v = Mml[1][row], m2v = Mml[2][row], m3v = Mml[3][row];
    float ms = fmaxf(fmaxf(m0v, m1v), fmaxf(m2v, m3v));
    float accv = 0.f, lacc = 0.f;
#pragma unroll
    for (int w = 0; w < 4; ++w) {
      float sc = exp2f(Mml[w][row] - ms);
      lacc += sc * Lml[w][row];
      accv += sc * OC[w][row * OCW + col];
    }
    out[(size_t)(b * T_ + q0 + row) * H_ + col] = accv / lacc;
  }
}

extern "C" void kernel_launch(void* const* d_in, const int* in_sizes, int n_in,
                              void* d_out, int out_size, void* d_ws, size_t ws_size,
                              hipStream_t stream) {
  const float* x  = (const float*)d_in[0];
  const float* Wq = (const float*)d_in[1];
  const float* Wk = (const float*)d_in[2];
  const float* Wv = (const float*)d_in[3];
  float* out = (float*)d_out;
  char* ws = (char*)d_ws;

  short* Wtf = (short*)(ws);                         // 768 KB
  short* Qf  = (short*)(ws + ((size_t)1 << 20));     // 4 MB
  short* Kf  = (short*)(ws + ((size_t)5 << 20));     // 4 MB
  short* Vf  = (short*)(ws + ((size_t)9 << 20));     // 4 MB  (total 13 MB)

  prep_wt<<<dim3(48), dim3(256), 0, stream>>>(Wq, Wk, Wv, Wtf);
  proj<<<dim3(512), dim3(256), 0, stream>>>(x, Wtf, Qf, Kf, Vf);
  attn<<<dim3(512), dim3(256), 0, stream>>>(Qf, Kf, Vf, out);
}

// Round 8
// 69.300 us; speedup vs baseline: 2.8543x; 1.0914x over previous
//
#include <hip/hip_runtime.h>

// Fused causal attention head: B=8, T=2048, C=1024, H=128 (fp32 in/out).
//   q,k,v = x@W{q,k,v};  out = softmax(tril(q k^T * C^-0.5)) @ v
// All intermediates (Wtf, Qf, Kf, Vf) are MFMA-fragment-major so every hot load
// is a coalesced `base + lane*16B` read (round-6 win).
//   QK-frag layout: frag(t16, k32) = 1KB contiguous;
//     idx(t,h) = ((t>>4)*NK + (h>>5))*512 + ((h>>3)&3)*128 + (t&15)*8 + (h&7)
//   V-frag layout: frag(t16, h16) = 512B contiguous;
//     idx(h,t) = ((t>>4)*8 + (h>>4))*256 + (h&15)*16 + (t&15)
// Round-8:
//   attn: per-SIMD load balancing. Block = (batch, p): waves 0-3 do q-group
//         63-p, waves 4-7 do q-group p -> block work const (~33 tiles), and
//         wave->SIMD round-robin gives each SIMD one hi + one lo wave
//         (round-7 had 8.8% occupancy = static imbalance, dur = max CU).
//         Plus T13 defer-max: skip O-rescale when __all(pm <= m+8).
//   proj: unchanged (bf16 LDS A-tile, reg-staged dbuf, 1 barrier/kt).
// Workspace (~13 MB): [0,768K) Wtf  [1M,5M) Qf  [5M,9M) Kf  [9M,13M) Vf

#define B_ 8
#define T_ 2048
#define C_ 1024
#define H_ 128

typedef __attribute__((ext_vector_type(4))) float  f32x4;
typedef __attribute__((ext_vector_type(8))) __bf16 bf16x8;
typedef __attribute__((ext_vector_type(4))) __bf16 bf16x4;
typedef __attribute__((ext_vector_type(4))) short  short4v;

#define QSCALE (0.03125f * 1.44269504088896340736f)  // C^-0.5 * log2(e)

static __device__ __forceinline__ short f2bf(float f) {
  union { __bf16 b; short s; } u;
  u.b = (__bf16)f;
  return u.s;
}

static __device__ __forceinline__ unsigned packbf2(float lo, float hi) {
  union { __bf16 b; unsigned short s; } a, c;
  a.b = (__bf16)lo; c.b = (__bf16)hi;
  return (unsigned)a.s | ((unsigned)c.s << 16);
}

// fragment-major index helpers
static __device__ __forceinline__ size_t qk_idx(int t, int h, int nk) {
  return ((size_t)((t >> 4) * nk + (h >> 5)) << 9) + (((h >> 3) & 3) << 7)
       + ((t & 15) << 3) + (h & 7);
}
static __device__ __forceinline__ size_t v_idx(int h, int t) {
  return ((size_t)((t >> 4) * 8 + (h >> 4)) << 8) + ((h & 15) << 4) + (t & 15);
}

// D = A(16x16) * B(16x16) + C, bf16, K=16.
static __device__ __forceinline__ f32x4 mfma16(unsigned a0, unsigned a1,
                                               unsigned b0, unsigned b1, f32x4 c) {
#if __has_builtin(__builtin_amdgcn_mfma_f32_16x16x16_bf16)
  union { unsigned u[2]; bf16x4 v; } ua, ub;
  ua.u[0] = a0; ua.u[1] = a1; ub.u[0] = b0; ub.u[1] = b1;
  return __builtin_amdgcn_mfma_f32_16x16x16_bf16(ua.v, ub.v, c, 0, 0, 0);
#elif __has_builtin(__builtin_amdgcn_mfma_f32_16x16x16bf16_1k)
  union { unsigned u[2]; short4v v; } ua, ub;
  ua.u[0] = a0; ua.u[1] = a1; ub.u[0] = b0; ub.u[1] = b1;
  return __builtin_amdgcn_mfma_f32_16x16x16bf16_1k(ua.v, ub.v, c, 0, 0, 0);
#else
  union { unsigned u[2]; short4v v; } ua, ub;
  ua.u[0] = a0; ua.u[1] = a1; ub.u[0] = b0; ub.u[1] = b1;
  f32x4 d = c;
  asm volatile("v_mfma_f32_16x16x16_bf16 %0, %1, %2, %0"
               : "+v"(d) : "v"(ua.v), "v"(ub.v));
  return d;
#endif
}

// ---------------- prep: Wtf frag-major; Wq pre-scaled by QSCALE -------------------
__global__ void prep_wt(const float* __restrict__ Wq, const float* __restrict__ Wk,
                        const float* __restrict__ Wv, short* __restrict__ Wtf) {
  __shared__ float L[64 * 129];
  const int mtx = blockIdx.x >> 4, kc = blockIdx.x & 15;
  const int k0 = kc * 64;
  const float* W = (mtx == 0) ? Wq : (mtx == 1 ? Wk : Wv);
  const float s = (mtx == 0) ? QSCALE : 1.0f;
  for (int i = threadIdx.x; i < 64 * 128; i += 256) {
    int kk = i >> 7, c = i & 127;
    L[kk * 129 + c] = W[(size_t)(k0 + kk) * H_ + c] * s;
  }
  __syncthreads();
  for (int i = threadIdx.x; i < 128 * 64; i += 256) {
    int n = i >> 6, kk = i & 63;
    Wtf[qk_idx(mtx * 128 + n, k0 + kk, 32)] = f2bf(L[kk * 129 + n]);
  }
}

// ---------------- proj: BM=64 x BN=192, BK=128, bf16 dbuf LDS, 4 waves, grid 512 --
__global__ __launch_bounds__(256) void proj(const float* __restrict__ x,
                                            const short* __restrict__ Wtf,
                                            short* __restrict__ Qf,
                                            short* __restrict__ Kf,
                                            short* __restrict__ Vf) {
  __shared__ __align__(16) short At[2][64 * 128];  // bf16 tiles, 16 KB each
  const int tid = threadIdx.x, lane = tid & 63, wv = tid >> 6;
  const int cg = lane & 15, rg = lane >> 4;
  const int lane8 = lane << 3;
  const int g = (blockIdx.x & 7) * 64 + (blockIdx.x >> 3);
  const int mb = g >> 1, bn = g & 1;
  const int m0 = mb * 64;
  const int nfrag0 = bn * 12 + wv * 3;
  const float* xblk = x + (size_t)m0 * C_;

  f32x4 acc[4][3];
#pragma unroll
  for (int i = 0; i < 4; ++i)
#pragma unroll
    for (int j = 0; j < 3; ++j) {
      f32x4 z = {0.f, 0.f, 0.f, 0.f};
      acc[i][j] = z;
    }

  f32x4 ldr[4][2];  // staging regs: 4 slots x 8 floats

#define PLOAD(kt)                                                              \
  { _Pragma("unroll") for (int it = 0; it < 4; ++it) {                         \
      int ls = it * 256 + tid; int r = ls >> 4, sc = ls & 15;                  \
      const float* p = xblk + (size_t)r * C_ + (kt) * 128 + sc * 8;            \
      ldr[it][0] = *(const f32x4*)p; ldr[it][1] = *(const f32x4*)(p + 4);      \
  } }

#define PWRITE(bf)                                                             \
  { _Pragma("unroll") for (int it = 0; it < 4; ++it) {                         \
      int ls = it * 256 + tid; int r = ls >> 4, sc = ls & 15;                  \
      bf16x8 tv;                                                               \
      tv[0] = (__bf16)ldr[it][0][0]; tv[1] = (__bf16)ldr[it][0][1];            \
      tv[2] = (__bf16)ldr[it][0][2]; tv[3] = (__bf16)ldr[it][0][3];            \
      tv[4] = (__bf16)ldr[it][1][0]; tv[5] = (__bf16)ldr[it][1][1];            \
      tv[6] = (__bf16)ldr[it][1][2]; tv[7] = (__bf16)ldr[it][1][3];            \
      *(bf16x8*)&At[bf][r * 128 + ((sc ^ (r & 7)) << 3)] = tv;                 \
  } }

  PLOAD(0);
  PWRITE(0);
  __syncthreads();

  for (int kt = 0; kt < 8; ++kt) {
    const int cur = kt & 1;
    if (kt < 7) PLOAD(kt + 1);   // issue next-tile loads before compute

#pragma unroll
    for (int ks = 0; ks < 4; ++ks) {
      bf16x8 af[4];
#pragma unroll
      for (int fm = 0; fm < 4; ++fm) {
        int r = fm * 16 + cg;
        int slot = (ks * 4 + rg) ^ (r & 7);
        af[fm] = *(const bf16x8*)&At[cur][r * 128 + (slot << 3)];
      }
#pragma unroll
      for (int nf = 0; nf < 3; ++nf) {
        bf16x8 bfr = *(const bf16x8*)&Wtf[((size_t)((nfrag0 + nf) * 32 + kt * 4 + ks) << 9) + lane8];
#pragma unroll
        for (int fm = 0; fm < 4; ++fm)
          acc[fm][nf] = __builtin_amdgcn_mfma_f32_16x16x32_bf16(af[fm], bfr, acc[fm][nf], 0, 0, 0);
      }
    }
    if (kt < 7) PWRITE(cur ^ 1);  // write target != read buffer
    __syncthreads();              // one barrier per kt
  }
#undef PLOAD
#undef PWRITE

#pragma unroll
  for (int fm = 0; fm < 4; ++fm) {
#pragma unroll
    for (int nf = 0; nf < 3; ++nf) {
      int n = (nfrag0 + nf) * 16 + cg;
      int rowm = m0 + fm * 16 + rg * 4;
      size_t boff = (size_t)(rowm >> 11) << 18;   // batch * 2048*128
      f32x4 v = acc[fm][nf];
      if (n < 128) {
#pragma unroll
        for (int r = 0; r < 4; ++r)
          Qf[boff + qk_idx((rowm + r) & 2047, n, 4)] = f2bf(v[r]);
      } else if (n < 256) {
#pragma unroll
        for (int r = 0; r < 4; ++r)
          Kf[boff + qk_idx((rowm + r) & 2047, n - 128, 4)] = f2bf(v[r]);
      } else {
#pragma unroll
        for (int r = 0; r < 4; ++r)
          Vf[boff + v_idx(n - 256, (rowm + r) & 2047)] = f2bf(v[r]);
      }
    }
  }
}

// ---------------- attn: paired q-groups, per-SIMD balanced ------------------------
// grid 256: b = bid&7 (XCD-local K/V), p = bid>>3 in [0,32).
// 8 waves: wv 0-3 -> qg = 63-p (kv-split 4), wv 4-7 -> qg = p (kv-split 4).
// Wave->SIMD is round-robin so each SIMD gets one hi + one lo wave: uniform load.
// Combine in 2 phases reusing OC[4] (70 KB LDS).
#define OCW 132  // 128 + 4 pad
__global__ __launch_bounds__(512) void attn(const short* __restrict__ Qf,
                                            const short* __restrict__ Kf,
                                            const short* __restrict__ Vf,
                                            float* __restrict__ out) {
  __shared__ __align__(16) float OC[4][32 * OCW];   // 67.6 KB, reused hi then lo
  __shared__ float Mml[8][32], Lml[8][32];
  const int tid = threadIdx.x, lane = tid & 63, wv = tid >> 6;
  const int cg = lane & 15, rg = lane >> 4;
  const int lane8 = lane << 3;
  const int bid = blockIdx.x;
  const int b = bid & 7;
  const int p = bid >> 3;                // 0..31
  const int grp = wv >> 2;               // 0 = hi group, 1 = lo group
  const int wvl = wv & 3;                // kv-split index within group
  const int qg = grp ? p : (63 - p);
  const int q0 = qg << 5;
  const int NT = (q0 + 95) >> 6;         // ceil((q0+32)/64) kv-tiles of 64
  const int SPW = (NT + 3) >> 2;
  const int t0 = wvl * SPW;
  const int t1 = (t0 + SPW < NT) ? (t0 + SPW) : NT;

  const short* Qp = Qf + ((size_t)b << 18);
  const short* Kp = Kf + ((size_t)b << 18);
  const short* Vp = Vf + ((size_t)b << 18);
  const float NEG_INF = -__builtin_inff();

  // Q frags (B-operand for swapped QK^T): coalesced frag reads
  bf16x8 qf[2][4];
#pragma unroll
  for (int qc = 0; qc < 2; ++qc)
#pragma unroll
    for (int ks = 0; ks < 4; ++ks)
      qf[qc][ks] = *(const bf16x8*)&Qp[((size_t)(((q0 >> 4) + qc) * 4 + ks) << 9) + lane8];

  f32x4 o[8][2];                         // O^T: o[hf][qc][r] = O[q][h=hf*16+rg*4+r]
#pragma unroll
  for (int f = 0; f < 8; ++f)
#pragma unroll
    for (int qc = 0; qc < 2; ++qc) { f32x4 z = {0.f, 0.f, 0.f, 0.f}; o[f][qc] = z; }
  float m[2] = {NEG_INF, NEG_INF}, lsum[2] = {0.0f, 0.0f};

  bf16x8 kf[4][4];
#define LOADK(t_)                                                              \
  { const short* ktp = Kp + (size_t)(t_) * 8192;                               \
    _Pragma("unroll") for (int nf_ = 0; nf_ < 4; ++nf_)                        \
    _Pragma("unroll") for (int ks_ = 0; ks_ < 4; ++ks_)                        \
      kf[nf_][ks_] = *(const bf16x8*)&ktp[((nf_ * 4 + ks_) << 9) + lane8]; }

  if (t0 < t1) LOADK(t0);

  for (int t = t0; t < t1; ++t) {
    const int kv0 = t * 64;
    const short* vtile = Vp + (size_t)t * 8192;

    f32x4 s[4][2];
#pragma unroll
    for (int nf = 0; nf < 4; ++nf)
#pragma unroll
      for (int qc = 0; qc < 2; ++qc) { f32x4 z = {0.f, 0.f, 0.f, 0.f}; s[nf][qc] = z; }

    // S^T = K Q^T
    __builtin_amdgcn_s_setprio(1);
#pragma unroll
    for (int nf = 0; nf < 4; ++nf)
#pragma unroll
      for (int ks = 0; ks < 4; ++ks) {
        s[nf][0] = __builtin_amdgcn_mfma_f32_16x16x32_bf16(kf[nf][ks], qf[0][ks], s[nf][0], 0, 0, 0);
        s[nf][1] = __builtin_amdgcn_mfma_f32_16x16x32_bf16(kf[nf][ks], qf[1][ks], s[nf][1], 0, 0, 0);
      }
    __builtin_amdgcn_s_setprio(0);

    // K software-pipeline: next tile into the same kf regs
    if (t + 1 < t1) LOADK(t + 1);

    // V nf0 prefetch
    unsigned v0a[8], v0b[8];
#pragma unroll
    for (int hf = 0; hf < 8; ++hf) {
      const unsigned* vp = (const unsigned*)&vtile[(hf << 8) + (cg << 4) + (rg << 2)];
      v0a[hf] = vp[0]; v0b[hf] = vp[1];
    }

    // causal mask (only the globally-last tile straddles the diagonal)
    if (t == NT - 1) {
#pragma unroll
      for (int nf = 0; nf < 4; ++nf)
#pragma unroll
        for (int qc = 0; qc < 2; ++qc)
#pragma unroll
          for (int r = 0; r < 4; ++r)
            if (kv0 + nf * 16 + rg * 4 + r > q0 + qc * 16 + cg) s[nf][qc][r] = NEG_INF;
    }

    // online softmax (exp2 domain) with T13 defer-max
    unsigned pk[4][2][2];
#pragma unroll
    for (int qc = 0; qc < 2; ++qc) {
      float pm = s[0][qc][0];
#pragma unroll
      for (int nf = 0; nf < 4; ++nf)
#pragma unroll
        for (int r = 0; r < 4; ++r) pm = fmaxf(pm, s[nf][qc][r]);
      pm = fmaxf(pm, __shfl_xor(pm, 16));
      pm = fmaxf(pm, __shfl_xor(pm, 32));   // full row max
      if (!__all(pm <= m[qc] + 8.0f)) {     // T13: rescale only on real growth
        float mn = fmaxf(m[qc], pm);
        float sf = exp2f(m[qc] - mn);       // first tile: exp2(-inf) = 0
        m[qc] = mn;
        lsum[qc] *= sf;
#pragma unroll
        for (int f = 0; f < 8; ++f)
#pragma unroll
          for (int r = 0; r < 4; ++r) o[f][qc][r] *= sf;
      }
      float mq = m[qc];
#pragma unroll
      for (int nf = 0; nf < 4; ++nf) {
        float p0 = exp2f(s[nf][qc][0] - mq), p1 = exp2f(s[nf][qc][1] - mq);
        float p2 = exp2f(s[nf][qc][2] - mq), p3 = exp2f(s[nf][qc][3] - mq);
        lsum[qc] += (p0 + p1) + (p2 + p3);
        pk[nf][qc][0] = packbf2(p0, p1);
        pk[nf][qc][1] = packbf2(p2, p3);
      }
    }

    // O^T += V^T P^T via 16x16x16
    __builtin_amdgcn_s_setprio(1);
#pragma unroll
    for (int hf = 0; hf < 8; ++hf) {
      o[hf][0] = mfma16(v0a[hf], v0b[hf], pk[0][0][0], pk[0][0][1], o[hf][0]);
      o[hf][1] = mfma16(v0a[hf], v0b[hf], pk[0][1][0], pk[0][1][1], o[hf][1]);
    }
#pragma unroll
    for (int nf = 1; nf < 4; ++nf) {
      const unsigned b00 = pk[nf][0][0], b01 = pk[nf][0][1];
      const unsigned b10 = pk[nf][1][0], b11 = pk[nf][1][1];
#pragma unroll
      for (int hf = 0; hf < 8; ++hf) {
        const unsigned* vp = (const unsigned*)&vtile[((nf * 8 + hf) << 8) + (cg << 4) + (rg << 2)];
        unsigned v0 = vp[0], v1 = vp[1];
        o[hf][0] = mfma16(v0, v1, b00, b01, o[hf][0]);
        o[hf][1] = mfma16(v0, v1, b10, b11, o[hf][1]);
      }
    }
    __builtin_amdgcn_s_setprio(0);
  }
#undef LOADK

  // reduce l across rg groups (same q); m already row-uniform
#pragma unroll
  for (int qc = 0; qc < 2; ++qc) {
    lsum[qc] += __shfl_xor(lsum[qc], 16);
    lsum[qc] += __shfl_xor(lsum[qc], 32);
  }
  if (lane < 16) {
#pragma unroll
    for (int qc = 0; qc < 2; ++qc) {
      Mml[wv][qc * 16 + lane] = m[qc];
      Lml[wv][qc * 16 + lane] = lsum[qc];
    }
  }
  // phase 1: hi waves park partial O^T; combine hi rows
  if (grp == 0) {
#pragma unroll
    for (int hf = 0; hf < 8; ++hf)
#pragma unroll
      for (int qc = 0; qc < 2; ++qc)
        *(f32x4*)&OC[wv][(qc * 16 + cg) * OCW + hf * 16 + rg * 4] = o[hf][qc];
  }
  __syncthreads();
  {
    const int qb = (63 - p) << 5;
    for (int i = tid; i < 32 * 128; i += 512) {
      int row = i >> 7, col = i & 127;
      float ms = fmaxf(fmaxf(Mml[0][row], Mml[1][row]), fmaxf(Mml[2][row], Mml[3][row]));
      float accv = 0.f, lacc = 0.f;
#pragma unroll
      for (int w = 0; w < 4; ++w) {
        float sc = exp2f(Mml[w][row] - ms);
        lacc += sc * Lml[w][row];
        accv += sc * OC[w][row * OCW + col];
      }
      out[(size_t)(b * T_ + qb + row) * H_ + col] = accv / lacc;
    }
  }
  __syncthreads();
  // phase 2: lo waves park; combine lo rows
  if (grp == 1) {
#pragma unroll
    for (int hf = 0; hf < 8; ++hf)
#pragma unroll
      for (int qc = 0; qc < 2; ++qc)
        *(f32x4*)&OC[wvl][(qc * 16 + cg) * OCW + hf * 16 + rg * 4] = o[hf][qc];
  }
  __syncthreads();
  {
    const int qb = p << 5;
    for (int i = tid; i < 32 * 128; i += 512) {
      int row = i >> 7, col = i & 127;
      float ms = fmaxf(fmaxf(Mml[4][row], Mml[5][row]), fmaxf(Mml[6][row], Mml[7][row]));
      float accv = 0.f, lacc = 0.f;
#pragma unroll
      for (int w = 0; w < 4; ++w) {
        float sc = exp2f(Mml[4 + w][row] - ms);
        lacc += sc * Lml[4 + w][row];
        accv += sc * OC[w][row * OCW + col];
      }
      out[(size_t)(b * T_ + qb + row) * H_ + col] = accv / lacc;
    }
  }
}

extern "C" void kernel_launch(void* const* d_in, const int* in_sizes, int n_in,
                              void* d_out, int out_size, void* d_ws, size_t ws_size,
                              hipStream_t stream) {
  const float* x  = (const float*)d_in[0];
  const float* Wq = (const float*)d_in[1];
  const float* Wk = (const float*)d_in[2];
  const float* Wv = (const float*)d_in[3];
  float* out = (float*)d_out;
  char* ws = (char*)d_ws;

  short* Wtf = (short*)(ws);                         // 768 KB
  short* Qf  = (short*)(ws + ((size_t)1 << 20));     // 4 MB
  short* Kf  = (short*)(ws + ((size_t)5 << 20));     // 4 MB
  short* Vf  = (short*)(ws + ((size_t)9 << 20));     // 4 MB  (total 13 MB)

  prep_wt<<<dim3(48), dim3(256), 0, stream>>>(Wq, Wk, Wv, Wtf);
  proj<<<dim3(512), dim3(256), 0, stream>>>(x, Wtf, Qf, Kf, Vf);
  attn<<<dim3(256), dim3(512), 0, stream>>>(Qf, Kf, Vf, out);
}